// Round 16
// baseline (1759.901 us; speedup 1.0000x reference)
//
#include <hip/hip_runtime.h>

#define DEV __device__ __forceinline__
typedef unsigned short u16;
typedef __bf16 bf16_t;
typedef bf16_t bf16x8 __attribute__((ext_vector_type(8)));
typedef float f32x4 __attribute__((ext_vector_type(4)));

DEV u16 f2bf(float f){ unsigned u=__float_as_uint(f); return (u16)((u + 0x7fffu + ((u>>16)&1u))>>16); }

DEV void gl_lds16(const void* g, void* l){
  __builtin_amdgcn_global_load_lds((__attribute__((address_space(1))) void*)g,
                                   (__attribute__((address_space(3))) void*)l, 16, 0, 0);
}
DEV f32x4 MFMA(bf16x8 a, bf16x8 b, f32x4 c){
  return __builtin_amdgcn_mfma_f32_16x16x32_bf16(a, b, c, 0, 0, 0);
}
DEV bf16x8 ld8(const u16* p){ return *(const bf16x8*)p; }

// ---------------- embedding lookup: x[row][:] = emb[idx[row]][:]
__global__ __launch_bounds__(256) void k_embed(const int* __restrict__ idx,
                                               const float* __restrict__ emb,
                                               float* __restrict__ x){
  int row = blockIdx.x;
  int tok = idx[row];
  const float4* s = (const float4*)(emb + (size_t)tok*1024);
  float4* d = (float4*)(x + (size_t)row*1024);
  d[threadIdx.x] = s[threadIdx.x];
}

// ---------------- layernorm (fp32 in) -> bf16 out, row = 1024
__global__ __launch_bounds__(256) void k_ln(const float* __restrict__ x,
                                            const float* __restrict__ sc,
                                            const float* __restrict__ bi,
                                            u16* __restrict__ out){
  int row = blockIdx.x;
  const float* xr = x + (size_t)row*1024;
  float4 v = ((const float4*)xr)[threadIdx.x];
  float s = v.x+v.y+v.z+v.w;
  float q = v.x*v.x+v.y*v.y+v.z*v.z+v.w*v.w;
  #pragma unroll
  for(int m=1;m<64;m<<=1){ s += __shfl_xor(s,m); q += __shfl_xor(q,m); }
  __shared__ float ss[4], sq[4];
  int w = threadIdx.x>>6;
  if((threadIdx.x&63)==0){ ss[w]=s; sq[w]=q; }
  __syncthreads();
  s = ss[0]+ss[1]+ss[2]+ss[3];
  q = sq[0]+sq[1]+sq[2]+sq[3];
  float mu = s*(1.f/1024.f);
  float var = q*(1.f/1024.f) - mu*mu;
  float rs = rsqrtf(var + 1e-5f);
  float4 sv = ((const float4*)sc)[threadIdx.x];
  float4 bv = ((const float4*)bi)[threadIdx.x];
  ushort4 o;
  o.x = f2bf((v.x-mu)*rs*sv.x + bv.x);
  o.y = f2bf((v.y-mu)*rs*sv.y + bv.y);
  o.z = f2bf((v.z-mu)*rs*sv.z + bv.z);
  o.w = f2bf((v.w-mu)*rs*sv.w + bv.w);
  *(ushort4*)(out + (size_t)row*1024 + threadIdx.x*4) = o;
}

// ---------------- transpose + convert: W[K][N] f32 -> Wt[N][K] bf16; z = layer
__global__ __launch_bounds__(256) void k_convT(const float* __restrict__ W,
                                               u16* __restrict__ Wt, int K, int N){
  __shared__ float tile[32][33];
  size_t loff = (size_t)blockIdx.z * K * N;
  W  += loff;  Wt += loff;
  int n0 = blockIdx.x*32, k0 = blockIdx.y*32;
  int tx = threadIdx.x & 31, ty = threadIdx.x >> 5;  // 32 x 8
  #pragma unroll
  for(int i=0;i<4;i++)
    tile[ty + i*8][tx] = W[(size_t)(k0 + ty + i*8)*N + n0 + tx];
  __syncthreads();
  #pragma unroll
  for(int i=0;i<4;i++)
    Wt[(size_t)(n0 + ty + i*8)*K + k0 + tx] = f2bf(tile[tx][ty + i*8]);
}

// ---------------- plain convert f32 -> bf16 (tok_emb), 4 elems/thread
__global__ __launch_bounds__(256) void k_conv(const float* __restrict__ in,
                                              u16* __restrict__ out, int n4){
  int i = blockIdx.x*256 + threadIdx.x;
  if(i < n4){
    float4 v = ((const float4*)in)[i];
    ushort4 o; o.x=f2bf(v.x); o.y=f2bf(v.y); o.z=f2bf(v.z); o.w=f2bf(v.w);
    ((ushort4*)out)[i] = o;
  }
}

// ---------------- GEMM 128x128 (2-barrier): C = A * Bt^T, BK=64, XOR swizzle
template<int EPI, int SWAP>
__global__ __launch_bounds__(256) void k_gemm(const u16* __restrict__ A,
                                              const u16* __restrict__ Bt,
                                              const float* __restrict__ bias,
                                              void* __restrict__ out,
                                              float* __restrict__ res,
                                              int M, int N, int K, int m_base){
  __shared__ __align__(16) u16 As[128*64];
  __shared__ __align__(16) u16 Bs[128*64];
  int t = threadIdx.x, l = t & 63, w = t >> 6;
  int g = l >> 4, lr = l & 15;
  int wr = w >> 1, wc = w & 1;
  int m0, n0;
  if constexpr(SWAP){ m0 = m_base + blockIdx.x*128; n0 = blockIdx.y*128; }
  else              { m0 = m_base + blockIdx.y*128; n0 = blockIdx.x*128; }
  f32x4 acc[4][4];
  #pragma unroll
  for(int i=0;i<4;i++)
    #pragma unroll
    for(int j=0;j<4;j++) acc[i][j] = f32x4{0.f,0.f,0.f,0.f};

  int sr = t >> 3;
  int sc = (((t & 7) ^ (sr & 7)) * 8);
  const u16* pa = A  + (size_t)(m0 + sr)*K + sc;
  const u16* pb = Bt + (size_t)(n0 + sr)*K + sc;
  u16* lda = As + t*8;
  u16* ldb = Bs + t*8;
  const int rs_a = (lr & 7)*8;

  for(int k0=0; k0<K; k0+=64){
    #pragma unroll
    for(int i=0;i<4;i++){
      gl_lds16(pa + (size_t)(i*32)*K, lda + i*2048);
      gl_lds16(pb + (size_t)(i*32)*K, ldb + i*2048);
    }
    pa += 64; pb += 64;
    __syncthreads();
    bf16x8 af[4][2], bfr[4][2];
    #pragma unroll
    for(int mi=0;mi<4;mi++){
      int row = wr*64 + mi*16 + lr;
      af[mi][0] = ld8(&As[row*64 + ((g*8     ) ^ rs_a)]);
      af[mi][1] = ld8(&As[row*64 + ((g*8 + 32) ^ rs_a)]);
    }
    #pragma unroll
    for(int ni=0;ni<4;ni++){
      int row = wc*64 + ni*16 + lr;
      bfr[ni][0] = ld8(&Bs[row*64 + ((g*8     ) ^ rs_a)]);
      bfr[ni][1] = ld8(&Bs[row*64 + ((g*8 + 32) ^ rs_a)]);
    }
    #pragma unroll
    for(int mi=0;mi<4;mi++)
      #pragma unroll
      for(int ni=0;ni<4;ni++){
        acc[mi][ni] = MFMA(af[mi][0], bfr[ni][0], acc[mi][ni]);
        acc[mi][ni] = MFMA(af[mi][1], bfr[ni][1], acc[mi][ni]);
      }
    __syncthreads();
  }

  float bv[4];
  #pragma unroll
  for(int ni=0;ni<4;ni++){
    if constexpr(EPI==3) bv[ni] = 0.f;
    else bv[ni] = bias[n0 + wc*64 + ni*16 + lr];
  }
  #pragma unroll
  for(int mi=0;mi<4;mi++){
    int row = m0 + wr*64 + mi*16 + g*4;
    #pragma unroll
    for(int ni=0;ni<4;ni++){
      int col = n0 + wc*64 + ni*16 + lr;
      #pragma unroll
      for(int r=0;r<4;r++){
        float v = acc[mi][ni][r] + bv[ni];
        size_t oidx = (size_t)(row + r)*N + col;
        if constexpr(EPI==0){
          ((u16*)out)[oidx] = f2bf(v);
        } else if constexpr(EPI==1){
          res[oidx] += v;
        } else if constexpr(EPI==2){
          float gv = 0.5f*v*(1.f + erff(v*0.70710678118654752f));
          ((u16*)out)[oidx] = f2bf(gv);
        } else {
          ((float*)out)[oidx] = v;   // f32 logits
        }
      }
    }
  }
}

// ---------------- GEMM 256x256 8-phase (head): C[M][N](f32) = A * Bt^T
// 512 thr = 8 waves x (32 rows x 256 cols). BK=64, double-buffered LDS.
// DEEP PREFETCH: ALL 8 gl_lds for tile j+1 issue at phase 0 of tile j
// (dest buffer's reads completed at tile j-1 close barrier). Ledger:
//  - ph1 close: vmcnt(8)  -> B1(j) done (issued 7 phases earlier, ~0 stall)
//  - ph3 close: vmcnt(2)  -> {A0,A1,B0}(j+1) done (issued 4 phases earlier)
// Tail tile issues nothing -> both waits no-ops.
__global__ __launch_bounds__(512) void k_gemm256(const u16* __restrict__ A,
                                                 const u16* __restrict__ Bt,
                                                 float* __restrict__ out,
                                                 int M, int N, int K, int m_base){
  __shared__ __align__(16) u16 As[2][256*64];
  __shared__ __align__(16) u16 Bs[2][256*64];
  int t = threadIdx.x, l = t & 63, wid = t >> 6;
  int g = l >> 4, lr = l & 15;
  int m0 = m_base + blockIdx.x*256, n0 = blockIdx.y*256;
  f32x4 acc[2][16];
  #pragma unroll
  for(int mi=0;mi<2;mi++)
    #pragma unroll
    for(int i=0;i<16;i++) acc[mi][i] = f32x4{0.f,0.f,0.f,0.f};

  int srow = t >> 3;                         // 0..63
  int scol = ((t & 7) ^ (srow & 7)) * 8;     // inverse-swizzled global col
  const int rs = (lr & 7) * 8;               // read-side XOR
  int nt = K >> 6;

  // stage whole tile jj (A0,A1,B0,B1 order = 8 gl_lds/thread)
  auto stage_tile = [&](int jj){
    int buf = jj & 1; int k0s = jj << 6;
    #pragma unroll
    for(int c=0;c<4;c++){
      int rr = c*64 + srow;
      gl_lds16(A + (size_t)(m0 + rr)*K + k0s + scol,
               &As[buf][rr*64 + (t&7)*8]);
    }
    #pragma unroll
    for(int c=0;c<4;c++){
      int rr = c*64 + srow;
      gl_lds16(Bt + (size_t)(n0 + rr)*K + k0s + scol,
               &Bs[buf][rr*64 + (t&7)*8]);
    }
  };

  // prologue: stage tile 0; wait {A0,A1,B0}; barrier
  stage_tile(0);
  asm volatile("s_waitcnt vmcnt(2)" ::: "memory");
  __builtin_amdgcn_s_barrier();
  __builtin_amdgcn_sched_barrier(0);

  bf16x8 af[2][2];
  for(int j=0; j<nt; ++j){
    const u16* Ab = As[j & 1];
    const u16* Bb = Bs[j & 1];
    bool pf = (j + 1 < nt);
    #pragma unroll
    for(int q=0; q<4; ++q){
      if(q == 0){
        #pragma unroll
        for(int mi=0;mi<2;mi++){
          int row = wid*32 + mi*16 + lr;
          af[mi][0] = ld8(&Ab[row*64 + ((g*8     ) ^ rs)]);
          af[mi][1] = ld8(&Ab[row*64 + ((g*8 + 32) ^ rs)]);
        }
      }
      bf16x8 bfr[4][2];
      #pragma unroll
      for(int i=0;i<4;i++){
        int row = (q*4 + i)*16 + lr;
        bfr[i][0] = ld8(&Bb[row*64 + ((g*8     ) ^ rs)]);
        bfr[i][1] = ld8(&Bb[row*64 + ((g*8 + 32) ^ rs)]);
      }
      if(q == 0 && pf) stage_tile(j+1);      // deep prefetch: whole next tile
      __builtin_amdgcn_s_barrier();          // open
      __builtin_amdgcn_sched_barrier(0);
      __builtin_amdgcn_s_setprio(1);
      #pragma unroll
      for(int mi=0;mi<2;mi++)
        #pragma unroll
        for(int i=0;i<4;i++){
          acc[mi][q*4+i] = MFMA(af[mi][0], bfr[i][0], acc[mi][q*4+i]);
          acc[mi][q*4+i] = MFMA(af[mi][1], bfr[i][1], acc[mi][q*4+i]);
        }
      __builtin_amdgcn_s_setprio(0);
      if(q == 1) asm volatile("s_waitcnt vmcnt(8)" ::: "memory");
      if(q == 3) asm volatile("s_waitcnt vmcnt(2)" ::: "memory");
      __builtin_amdgcn_s_barrier();          // close
      __builtin_amdgcn_sched_barrier(0);
    }
  }

  #pragma unroll
  for(int mi=0;mi<2;mi++){
    int row = m0 + wid*32 + mi*16 + g*4;
    #pragma unroll
    for(int i=0;i<16;i++){
      int col = n0 + i*16 + lr;
      #pragma unroll
      for(int r=0;r<4;r++)
        out[(size_t)(row + r)*N + col] = acc[mi][i][r];
    }
  }
}

// ---------------- head GEMM fallback (small-ws only): BK=32 reg-staged B
__global__ __launch_bounds__(256) void k_gemm_f32b(const u16* __restrict__ A,
                                                   const float* __restrict__ B,
                                                   float* __restrict__ out,
                                                   int M, int N, int K, int m_base){
  __shared__ __align__(16) u16 As[128*32];
  __shared__ __align__(16) u16 Bs[128*32];
  int t = threadIdx.x, l = t & 63, w = t >> 6;
  int g = l >> 4, lr = l & 15;
  int wr = w >> 1, wc = w & 1;
  int m0 = m_base + blockIdx.y*128, n0 = blockIdx.x*128;
  f32x4 acc[4][4];
  #pragma unroll
  for(int i=0;i<4;i++)
    #pragma unroll
    for(int j=0;j<4;j++) acc[i][j] = f32x4{0.f,0.f,0.f,0.f};

  int r0 = t >> 2, c0 = (t & 3)*8;
  const u16* pa0 = A + (size_t)(m0 + r0)*K + c0;
  const u16* pa1 = A + (size_t)(m0 + r0 + 64)*K + c0;
  u16* la0 = As + t*8;  u16* la1 = As + (t+256)*8;
  int br = t >> 1, bc = (t & 1)*16;
  const float* pb = B + (size_t)(n0 + br)*K + bc;

  for(int k0=0; k0<K; k0+=32){
    gl_lds16(pa0, la0); gl_lds16(pa1, la1);
    pa0 += 32; pa1 += 32;
    float4 f0 = ((const float4*)pb)[0];
    float4 f1 = ((const float4*)pb)[1];
    float4 f2 = ((const float4*)pb)[2];
    float4 f3 = ((const float4*)pb)[3];
    pb += 32;
    ushort4 u0{f2bf(f0.x),f2bf(f0.y),f2bf(f0.z),f2bf(f0.w)};
    ushort4 u1{f2bf(f1.x),f2bf(f1.y),f2bf(f1.z),f2bf(f1.w)};
    ushort4 u2{f2bf(f2.x),f2bf(f2.y),f2bf(f2.z),f2bf(f2.w)};
    ushort4 u3{f2bf(f3.x),f2bf(f3.y),f2bf(f3.z),f2bf(f3.w)};
    *(ushort4*)&Bs[br*32 + bc +  0] = u0;
    *(ushort4*)&Bs[br*32 + bc +  4] = u1;
    *(ushort4*)&Bs[br*32 + bc +  8] = u2;
    *(ushort4*)&Bs[br*32 + bc + 12] = u3;
    __syncthreads();
    bf16x8 af[4], bfr[4];
    #pragma unroll
    for(int mi=0;mi<4;mi++) af[mi]  = ld8(&As[(wr*64 + mi*16 + lr)*32 + g*8]);
    #pragma unroll
    for(int ni=0;ni<4;ni++) bfr[ni] = ld8(&Bs[(wc*64 + ni*16 + lr)*32 + g*8]);
    #pragma unroll
    for(int mi=0;mi<4;mi++)
      #pragma unroll
      for(int ni=0;ni<4;ni++)
        acc[mi][ni] = MFMA(af[mi], bfr[ni], acc[mi][ni]);
    __syncthreads();
  }

  #pragma unroll
  for(int mi=0;mi<4;mi++){
    int row = m0 + wr*64 + mi*16 + g*4;
    #pragma unroll
    for(int ni=0;ni<4;ni++){
      int col = n0 + wc*64 + ni*16 + lr;
      #pragma unroll
      for(int r=0;r<4;r++)
        out[(size_t)(row + r)*N + col] = acc[mi][ni][r];
    }
  }
}

// ---------------- flash attention, causal + ALiBi, GQA (H=16, KVH=4, HD=64)
__global__ __launch_bounds__(256) void k_attn(const u16* __restrict__ qkv,
                                              u16* __restrict__ atto){
  __shared__ __align__(16) u16 Ksm[64*72];
  __shared__ __align__(16) u16 Vsm[64*72];
  __shared__ __align__(16) u16 Psm[4][16*72];
  int t = threadIdx.x, l = t & 63, w = t >> 6, g = l >> 4, lr = l & 15;
  int bh = blockIdx.y; int b = bh >> 4, h = bh & 15, kvh = h >> 2;
  int qb = blockIdx.x * 64;
  const float L2E = 1.44269504088896f;
  const float C1  = 0.125f * L2E;
  float slopeL = exp2f(-0.5f*(float)(h+1)) * L2E;
  float sLkt[4];
  #pragma unroll
  for(int kt=0;kt<4;kt++) sLkt[kt] = slopeL*(float)(kt*16+lr);

  int qrow = qb + w*16 + lr;
  const u16* qp = qkv + (size_t)(b*2048 + qrow)*1536 + h*64;
  bf16x8 qf0 = ld8(qp + g*8);
  bf16x8 qf1 = ld8(qp + 32 + g*8);

  bf16_t onev = (bf16_t)1.0f;
  bf16x8 onesb = {onev,onev,onev,onev,onev,onev,onev,onev};

  f32x4 oacc[4];
  #pragma unroll
  for(int i=0;i<4;i++) oacc[i] = f32x4{0.f,0.f,0.f,0.f};
  f32x4 lsum = f32x4{0.f,0.f,0.f,0.f};

  int nkb = blockIdx.x + 1;
  for(int kb=0; kb<nkb; kb++){
    __syncthreads();
    #pragma unroll
    for(int i=0;i<2;i++){
      int tt = t + i*256;
      int key = tt >> 3, ho = (tt & 7)*8;
      const u16* src = qkv + (size_t)(b*2048 + kb*64 + key)*1536 + 1024 + kvh*64 + ho;
      *(int4*)&Ksm[key*72 + ho] = *(const int4*)src;
    }
    {
      int key0 = (t>>3)*2, hd0 = (t&7)*8;
      const u16* v0 = qkv + (size_t)(b*2048 + kb*64 + key0)*1536 + 1280 + kvh*64 + hd0;
      int4 A0 = *(const int4*)v0;
      int4 A1 = *(const int4*)(v0 + 1536);
      const u16* ua = (const u16*)&A0; const u16* ub = (const u16*)&A1;
      #pragma unroll
      for(int j=0;j<8;j++){
        int row = hd0 + j;
        int colp = key0 ^ ((row>>3)*8);
        unsigned pr = (unsigned)ua[j] | ((unsigned)ub[j]<<16);
        *(unsigned*)&Vsm[row*72 + colp] = pr;
      }
    }
    __syncthreads();
    f32x4 sacc[4];
    #pragma unroll
    for(int kt=0;kt<4;kt++) sacc[kt] = f32x4{0.f,0.f,0.f,0.f};
    #pragma unroll
    for(int kt=0;kt<4;kt++){
      bf16x8 kf0 = ld8(&Ksm[(kt*16+lr)*72 + g*8]);
      bf16x8 kf1 = ld8(&Ksm[(kt*16+lr)*72 + 32 + g*8]);
      sacc[kt] = MFMA(qf0, kf0, sacc[kt]);
      sacc[kt] = MFMA(qf1, kf1, sacc[kt]);
    }
    #pragma unroll
    for(int r=0;r<4;r++){
      int q = qb + w*16 + g*4 + r;
      float base = slopeL*(float)(kb*64 - q) - 8.0f*L2E;
      #pragma unroll
      for(int kt=0;kt<4;kt++){
        int key = kb*64 + kt*16 + lr;
        float f = fmaf(sacc[kt][r], C1, base + sLkt[kt]);
        float p = (key <= q) ? exp2f(f) : 0.f;
        Psm[w][(g*4+r)*72 + kt*16 + lr] = f2bf(p);
      }
    }
    #pragma unroll
    for(int ks=0;ks<2;ks++){
      bf16x8 pf = ld8(&Psm[w][lr*72 + ks*32 + g*8]);
      lsum = MFMA(pf, onesb, lsum);
      #pragma unroll
      for(int ht=0;ht<4;ht++){
        int row = ht*16 + lr;
        int colp = (ks*32 + g*8) ^ ((row>>3)*8);
        bf16x8 vf = ld8(&Vsm[row*72 + colp]);
        oacc[ht] = MFMA(pf, vf, oacc[ht]);
      }
    }
  }
  #pragma unroll
  for(int ht=0;ht<4;ht++){
    #pragma unroll
    for(int r=0;r<4;r++){
      float o = oacc[ht][r] / lsum[r];
      atto[(size_t)(b*2048 + qb + w*16 + g*4 + r)*1024 + h*64 + ht*16 + lr] = f2bf(o);
    }
  }
}

extern "C" void kernel_launch(void* const* d_in, const int* in_sizes, int n_in,
                              void* d_out, int out_size, void* d_ws, size_t ws_size,
                              hipStream_t stream) {
  const float* tok_emb = (const float*)d_in[0];
  const float* ln1_s   = (const float*)d_in[1];
  const float* ln1_b   = (const float*)d_in[2];
  const float* qkv_w   = (const float*)d_in[3];
  const float* qkv_b   = (const float*)d_in[4];
  const float* proj_w  = (const float*)d_in[5];
  const float* proj_b  = (const float*)d_in[6];
  const float* ln2_s   = (const float*)d_in[7];
  const float* ln2_b   = (const float*)d_in[8];
  const float* fc1_w   = (const float*)d_in[9];
  const float* fc1_b   = (const float*)d_in[10];
  const float* fc2_w   = (const float*)d_in[11];
  const float* fc2_b   = (const float*)d_in[12];
  const float* lnf_s   = (const float*)d_in[13];
  const float* lnf_b   = (const float*)d_in[14];
  const int*   idx     = (const int*)d_in[15];

  // scratch plan inside d_out (524 MB, f32 logits written last):
  char* ob = (char*)d_out;
  float* xf32  = (float*)(ob);                                 //  0   .. 16.8 MB
  u16* qkv_bf  = (u16*)(ob + (size_t)16777216);                // 16.8 .. 29.4
  u16* atto_bf = (u16*)(ob + (size_t)29360128);                // 29.4 .. 37.7
  u16* mid_bf  = (u16*)(ob + (size_t)37748736);                // 37.7 .. 71.3
  u16* wt_qkv  = (u16*)(ob + (size_t)71303168);                // 71.3 .. 83.9
  u16* wt_proj = (u16*)(ob + (size_t)83886080);                // 83.9 .. 92.3
  u16* wt_fc1  = (u16*)(ob + (size_t)92274688);                // 92.3 ..125.8
  u16* wt_fc2  = (u16*)(ob + (size_t)125829120);               //125.8 ..159.4
  u16* h_bf    = (u16*)d_ws;                                   //  8.4 MB
  float* out   = (float*)d_out;

  bool big_ws = ws_size >= (size_t)(8388608 + 65536000);
  // fallback te: rows 2304..2816 of output (f32 bytes 294912000..360448000)
  u16* te_bf = big_ws ? (u16*)((char*)d_ws + 8388608)
                      : (u16*)(ob + (size_t)294912000);

  k_conv<<<32000, 256, 0, stream>>>(tok_emb, te_bf, 8192000);
  k_embed<<<4096, 256, 0, stream>>>(idx, tok_emb, xf32);
  k_convT<<<dim3(48,32,4), 256, 0, stream>>>(qkv_w,  wt_qkv, 1024, 1536);
  k_convT<<<dim3(32,32,4), 256, 0, stream>>>(proj_w, wt_proj, 1024, 1024);
  k_convT<<<dim3(128,32,4), 256, 0, stream>>>(fc1_w, wt_fc1, 1024, 4096);
  k_convT<<<dim3(32,128,4), 256, 0, stream>>>(fc2_w, wt_fc2, 4096, 1024);

  for(int l=0; l<4; l++){
    k_ln<<<4096, 256, 0, stream>>>(xf32, ln1_s + (size_t)l*1024, ln1_b + (size_t)l*1024, h_bf);
    k_gemm<0,0><<<dim3(12,32), 256, 0, stream>>>(h_bf, wt_qkv + (size_t)l*1536*1024,
                                                 qkv_b + (size_t)l*1536,
                                                 qkv_bf, nullptr, 4096, 1536, 1024, 0);
    k_attn<<<dim3(32,32), 256, 0, stream>>>(qkv_bf, atto_bf);
    k_gemm<1,0><<<dim3(8,32), 256, 0, stream>>>(atto_bf, wt_proj + (size_t)l*1024*1024,
                                                proj_b + (size_t)l*1024,
                                                nullptr, xf32, 4096, 1024, 1024, 0);
    k_ln<<<4096, 256, 0, stream>>>(xf32, ln2_s + (size_t)l*1024, ln2_b + (size_t)l*1024, h_bf);
    k_gemm<2,0><<<dim3(32,32), 256, 0, stream>>>(h_bf, wt_fc1 + (size_t)l*4096*1024,
                                                 fc1_b + (size_t)l*4096,
                                                 mid_bf, nullptr, 4096, 4096, 1024, 0);
    k_gemm<1,0><<<dim3(8,32), 256, 0, stream>>>(mid_bf, wt_fc2 + (size_t)l*1024*4096,
                                                fc2_b + (size_t)l*1024,
                                                nullptr, xf32, 4096, 1024, 4096, 0);
  }
  k_ln<<<4096, 256, 0, stream>>>(xf32, lnf_s, lnf_b, h_bf);

  if(big_ws){
    // head: 256x256 8-phase deep-prefetch, row-tiles on x for B-panel L2 reuse
    k_gemm256<<<dim3(16,125), 512, 0, stream>>>(h_bf, te_bf, out,
                                                4096, 32000, 1024, 0);
  } else {
    // te at rows 2304..2815 -> 256-tiles 9,10 conflict; fast tiles 0-8 & 11-15
    k_gemm256<<<dim3(9,125), 512, 0, stream>>>(h_bf, te_bf, out,
                                               4096, 32000, 1024, 0);
    k_gemm256<<<dim3(5,125), 512, 0, stream>>>(h_bf, te_bf, out,
                                               4096, 32000, 1024, 2816);
    k_gemm_f32b<<<dim3(250,4), 256, 0, stream>>>(h_bf, tok_emb, out,
                                                 4096, 32000, 1024, 2304);
  }
}

// Round 17
// 1603.776 us; speedup vs baseline: 1.0973x; 1.0973x over previous
//
#include <hip/hip_runtime.h>

#define DEV __device__ __forceinline__
typedef unsigned short u16;
typedef __bf16 bf16_t;
typedef bf16_t bf16x8 __attribute__((ext_vector_type(8)));
typedef float f32x4 __attribute__((ext_vector_type(4)));

DEV u16 f2bf(float f){ unsigned u=__float_as_uint(f); return (u16)((u + 0x7fffu + ((u>>16)&1u))>>16); }

DEV void gl_lds16(const void* g, void* l){
  __builtin_amdgcn_global_load_lds((__attribute__((address_space(1))) void*)g,
                                   (__attribute__((address_space(3))) void*)l, 16, 0, 0);
}
DEV f32x4 MFMA(bf16x8 a, bf16x8 b, f32x4 c){
  return __builtin_amdgcn_mfma_f32_16x16x32_bf16(a, b, c, 0, 0, 0);
}
DEV bf16x8 ld8(const u16* p){ return *(const bf16x8*)p; }

// ---------------- embedding lookup: x[row][:] = emb[idx[row]][:]
__global__ __launch_bounds__(256) void k_embed(const int* __restrict__ idx,
                                               const float* __restrict__ emb,
                                               float* __restrict__ x){
  int row = blockIdx.x;
  int tok = idx[row];
  const float4* s = (const float4*)(emb + (size_t)tok*1024);
  float4* d = (float4*)(x + (size_t)row*1024);
  d[threadIdx.x] = s[threadIdx.x];
}

// ---------------- layernorm (fp32 in) -> bf16 out, row = 1024
__global__ __launch_bounds__(256) void k_ln(const float* __restrict__ x,
                                            const float* __restrict__ sc,
                                            const float* __restrict__ bi,
                                            u16* __restrict__ out){
  int row = blockIdx.x;
  const float* xr = x + (size_t)row*1024;
  float4 v = ((const float4*)xr)[threadIdx.x];
  float s = v.x+v.y+v.z+v.w;
  float q = v.x*v.x+v.y*v.y+v.z*v.z+v.w*v.w;
  #pragma unroll
  for(int m=1;m<64;m<<=1){ s += __shfl_xor(s,m); q += __shfl_xor(q,m); }
  __shared__ float ss[4], sq[4];
  int w = threadIdx.x>>6;
  if((threadIdx.x&63)==0){ ss[w]=s; sq[w]=q; }
  __syncthreads();
  s = ss[0]+ss[1]+ss[2]+ss[3];
  q = sq[0]+sq[1]+sq[2]+sq[3];
  float mu = s*(1.f/1024.f);
  float var = q*(1.f/1024.f) - mu*mu;
  float rs = rsqrtf(var + 1e-5f);
  float4 sv = ((const float4*)sc)[threadIdx.x];
  float4 bv = ((const float4*)bi)[threadIdx.x];
  ushort4 o;
  o.x = f2bf((v.x-mu)*rs*sv.x + bv.x);
  o.y = f2bf((v.y-mu)*rs*sv.y + bv.y);
  o.z = f2bf((v.z-mu)*rs*sv.z + bv.z);
  o.w = f2bf((v.w-mu)*rs*sv.w + bv.w);
  *(ushort4*)(out + (size_t)row*1024 + threadIdx.x*4) = o;
}

// ---------------- transpose + convert: W[K][N] f32 -> Wt[N][K] bf16; z = layer
__global__ __launch_bounds__(256) void k_convT(const float* __restrict__ W,
                                               u16* __restrict__ Wt, int K, int N){
  __shared__ float tile[32][33];
  size_t loff = (size_t)blockIdx.z * K * N;
  W  += loff;  Wt += loff;
  int n0 = blockIdx.x*32, k0 = blockIdx.y*32;
  int tx = threadIdx.x & 31, ty = threadIdx.x >> 5;  // 32 x 8
  #pragma unroll
  for(int i=0;i<4;i++)
    tile[ty + i*8][tx] = W[(size_t)(k0 + ty + i*8)*N + n0 + tx];
  __syncthreads();
  #pragma unroll
  for(int i=0;i<4;i++)
    Wt[(size_t)(n0 + ty + i*8)*K + k0 + tx] = f2bf(tile[tx][ty + i*8]);
}

// ---------------- plain convert f32 -> bf16 (tok_emb), 4 elems/thread
__global__ __launch_bounds__(256) void k_conv(const float* __restrict__ in,
                                              u16* __restrict__ out, int n4){
  int i = blockIdx.x*256 + threadIdx.x;
  if(i < n4){
    float4 v = ((const float4*)in)[i];
    ushort4 o; o.x=f2bf(v.x); o.y=f2bf(v.y); o.z=f2bf(v.z); o.w=f2bf(v.w);
    ((ushort4*)out)[i] = o;
  }
}

// ---------------- GEMM 128x128 (2-barrier): C = A * Bt^T, BK=64, XOR swizzle
template<int EPI, int SWAP>
__global__ __launch_bounds__(256) void k_gemm(const u16* __restrict__ A,
                                              const u16* __restrict__ Bt,
                                              const float* __restrict__ bias,
                                              void* __restrict__ out,
                                              float* __restrict__ res,
                                              int M, int N, int K, int m_base){
  __shared__ __align__(16) u16 As[128*64];
  __shared__ __align__(16) u16 Bs[128*64];
  int t = threadIdx.x, l = t & 63, w = t >> 6;
  int g = l >> 4, lr = l & 15;
  int wr = w >> 1, wc = w & 1;
  int m0, n0;
  if constexpr(SWAP){ m0 = m_base + blockIdx.x*128; n0 = blockIdx.y*128; }
  else              { m0 = m_base + blockIdx.y*128; n0 = blockIdx.x*128; }
  f32x4 acc[4][4];
  #pragma unroll
  for(int i=0;i<4;i++)
    #pragma unroll
    for(int j=0;j<4;j++) acc[i][j] = f32x4{0.f,0.f,0.f,0.f};

  int sr = t >> 3;
  int sc = (((t & 7) ^ (sr & 7)) * 8);
  const u16* pa = A  + (size_t)(m0 + sr)*K + sc;
  const u16* pb = Bt + (size_t)(n0 + sr)*K + sc;
  u16* lda = As + t*8;
  u16* ldb = Bs + t*8;
  const int rs_a = (lr & 7)*8;

  for(int k0=0; k0<K; k0+=64){
    #pragma unroll
    for(int i=0;i<4;i++){
      gl_lds16(pa + (size_t)(i*32)*K, lda + i*2048);
      gl_lds16(pb + (size_t)(i*32)*K, ldb + i*2048);
    }
    pa += 64; pb += 64;
    __syncthreads();
    bf16x8 af[4][2], bfr[4][2];
    #pragma unroll
    for(int mi=0;mi<4;mi++){
      int row = wr*64 + mi*16 + lr;
      af[mi][0] = ld8(&As[row*64 + ((g*8     ) ^ rs_a)]);
      af[mi][1] = ld8(&As[row*64 + ((g*8 + 32) ^ rs_a)]);
    }
    #pragma unroll
    for(int ni=0;ni<4;ni++){
      int row = wc*64 + ni*16 + lr;
      bfr[ni][0] = ld8(&Bs[row*64 + ((g*8     ) ^ rs_a)]);
      bfr[ni][1] = ld8(&Bs[row*64 + ((g*8 + 32) ^ rs_a)]);
    }
    #pragma unroll
    for(int mi=0;mi<4;mi++)
      #pragma unroll
      for(int ni=0;ni<4;ni++){
        acc[mi][ni] = MFMA(af[mi][0], bfr[ni][0], acc[mi][ni]);
        acc[mi][ni] = MFMA(af[mi][1], bfr[ni][1], acc[mi][ni]);
      }
    __syncthreads();
  }

  float bv[4];
  #pragma unroll
  for(int ni=0;ni<4;ni++){
    if constexpr(EPI==3) bv[ni] = 0.f;
    else bv[ni] = bias[n0 + wc*64 + ni*16 + lr];
  }
  #pragma unroll
  for(int mi=0;mi<4;mi++){
    int row = m0 + wr*64 + mi*16 + g*4;
    #pragma unroll
    for(int ni=0;ni<4;ni++){
      int col = n0 + wc*64 + ni*16 + lr;
      #pragma unroll
      for(int r=0;r<4;r++){
        float v = acc[mi][ni][r] + bv[ni];
        size_t oidx = (size_t)(row + r)*N + col;
        if constexpr(EPI==0){
          ((u16*)out)[oidx] = f2bf(v);
        } else if constexpr(EPI==1){
          res[oidx] += v;
        } else if constexpr(EPI==2){
          float gv = 0.5f*v*(1.f + erff(v*0.70710678118654752f));
          ((u16*)out)[oidx] = f2bf(gv);
        } else {
          ((float*)out)[oidx] = v;   // f32 logits
        }
      }
    }
  }
}

// ---------------- GEMM 128x64 narrow (proj/fc2): 512 blocks -> 2/CU occupancy
// 4 waves as 2x2 over 64x32 sub-tiles; EPI=1 (bias + res+=) only.
__global__ __launch_bounds__(256) void k_gemm_n64(const u16* __restrict__ A,
                                                  const u16* __restrict__ Bt,
                                                  const float* __restrict__ bias,
                                                  float* __restrict__ res,
                                                  int M, int N, int K){
  __shared__ __align__(16) u16 As[128*64];
  __shared__ __align__(16) u16 Bs[64*64];
  int t = threadIdx.x, l = t & 63, w = t >> 6;
  int g = l >> 4, lr = l & 15;
  int wr = w >> 1, wc = w & 1;
  int m0 = blockIdx.y*128, n0 = blockIdx.x*64;
  f32x4 acc[4][2];
  #pragma unroll
  for(int i=0;i<4;i++)
    #pragma unroll
    for(int j=0;j<2;j++) acc[i][j] = f32x4{0.f,0.f,0.f,0.f};

  int sr = t >> 3;
  int sc = (((t & 7) ^ (sr & 7)) * 8);
  const u16* pa = A  + (size_t)(m0 + sr)*K + sc;
  const u16* pb = Bt + (size_t)(n0 + sr)*K + sc;
  u16* lda = As + t*8;
  u16* ldb = Bs + t*8;
  const int rs_a = (lr & 7)*8;

  for(int k0=0; k0<K; k0+=64){
    #pragma unroll
    for(int i=0;i<4;i++)
      gl_lds16(pa + (size_t)(i*32)*K, lda + i*2048);
    #pragma unroll
    for(int i=0;i<2;i++)
      gl_lds16(pb + (size_t)(i*32)*K, ldb + i*2048);
    pa += 64; pb += 64;
    __syncthreads();
    bf16x8 af[4][2], bfr[2][2];
    #pragma unroll
    for(int mi=0;mi<4;mi++){
      int row = wr*64 + mi*16 + lr;
      af[mi][0] = ld8(&As[row*64 + ((g*8     ) ^ rs_a)]);
      af[mi][1] = ld8(&As[row*64 + ((g*8 + 32) ^ rs_a)]);
    }
    #pragma unroll
    for(int ni=0;ni<2;ni++){
      int row = wc*32 + ni*16 + lr;
      bfr[ni][0] = ld8(&Bs[row*64 + ((g*8     ) ^ rs_a)]);
      bfr[ni][1] = ld8(&Bs[row*64 + ((g*8 + 32) ^ rs_a)]);
    }
    #pragma unroll
    for(int mi=0;mi<4;mi++)
      #pragma unroll
      for(int ni=0;ni<2;ni++){
        acc[mi][ni] = MFMA(af[mi][0], bfr[ni][0], acc[mi][ni]);
        acc[mi][ni] = MFMA(af[mi][1], bfr[ni][1], acc[mi][ni]);
      }
    __syncthreads();
  }

  float bv[2];
  #pragma unroll
  for(int ni=0;ni<2;ni++) bv[ni] = bias[n0 + wc*32 + ni*16 + lr];
  #pragma unroll
  for(int mi=0;mi<4;mi++){
    int row = m0 + wr*64 + mi*16 + g*4;
    #pragma unroll
    for(int ni=0;ni<2;ni++){
      int col = n0 + wc*32 + ni*16 + lr;
      #pragma unroll
      for(int r=0;r<4;r++)
        res[(size_t)(row + r)*N + col] += acc[mi][ni][r] + bv[ni];
    }
  }
}

// ---------------- GEMM 256x256 8-phase (head) — r15 schedule (proven 354us):
// one half-tile staged per phase; vmcnt(2) prologue/ph3, vmcnt(4) ph1.
__global__ __launch_bounds__(512) void k_gemm256(const u16* __restrict__ A,
                                                 const u16* __restrict__ Bt,
                                                 float* __restrict__ out,
                                                 int M, int N, int K, int m_base){
  __shared__ __align__(16) u16 As[2][256*64];
  __shared__ __align__(16) u16 Bs[2][256*64];
  int t = threadIdx.x, l = t & 63, wid = t >> 6;
  int g = l >> 4, lr = l & 15;
  int m0 = m_base + blockIdx.x*256, n0 = blockIdx.y*256;
  f32x4 acc[2][16];
  #pragma unroll
  for(int mi=0;mi<2;mi++)
    #pragma unroll
    for(int i=0;i<16;i++) acc[mi][i] = f32x4{0.f,0.f,0.f,0.f};

  int srow = t >> 3;                         // 0..63
  int scol = ((t & 7) ^ (srow & 7)) * 8;     // inverse-swizzled global col
  const int rs = (lr & 7) * 8;               // read-side XOR
  int nt = K >> 6;

  auto stage_half = [&](int jj, int h){
    int buf = jj & 1; int k0s = jj << 6;
    if(h < 2){
      #pragma unroll
      for(int c=0;c<2;c++){
        int rr = h*128 + c*64 + srow;
        gl_lds16(A + (size_t)(m0 + rr)*K + k0s + scol,
                 &As[buf][rr*64 + (t&7)*8]);
      }
    } else {
      #pragma unroll
      for(int c=0;c<2;c++){
        int rr = (h-2)*128 + c*64 + srow;
        gl_lds16(Bt + (size_t)(n0 + rr)*K + k0s + scol,
                 &Bs[buf][rr*64 + (t&7)*8]);
      }
    }
  };

  // prologue: stage tile 0 fully; wait all but B1 (B1 needed at phase 2)
  stage_half(0,0); stage_half(0,1); stage_half(0,2); stage_half(0,3);
  asm volatile("s_waitcnt vmcnt(2)" ::: "memory");
  __builtin_amdgcn_s_barrier();
  __builtin_amdgcn_sched_barrier(0);

  bf16x8 af[2][2];
  for(int j=0; j<nt; ++j){
    const u16* Ab = As[j & 1];
    const u16* Bb = Bs[j & 1];
    bool pf = (j + 1 < nt);
    #pragma unroll
    for(int q=0; q<4; ++q){
      if(q == 0){
        #pragma unroll
        for(int mi=0;mi<2;mi++){
          int row = wid*32 + mi*16 + lr;
          af[mi][0] = ld8(&Ab[row*64 + ((g*8     ) ^ rs)]);
          af[mi][1] = ld8(&Ab[row*64 + ((g*8 + 32) ^ rs)]);
        }
      }
      bf16x8 bfr[4][2];
      #pragma unroll
      for(int i=0;i<4;i++){
        int row = (q*4 + i)*16 + lr;
        bfr[i][0] = ld8(&Bb[row*64 + ((g*8     ) ^ rs)]);
        bfr[i][1] = ld8(&Bb[row*64 + ((g*8 + 32) ^ rs)]);
      }
      if(pf) stage_half(j+1, q);
      __builtin_amdgcn_s_barrier();          // open
      __builtin_amdgcn_sched_barrier(0);
      __builtin_amdgcn_s_setprio(1);
      #pragma unroll
      for(int mi=0;mi<2;mi++)
        #pragma unroll
        for(int i=0;i<4;i++){
          acc[mi][q*4+i] = MFMA(af[mi][0], bfr[i][0], acc[mi][q*4+i]);
          acc[mi][q*4+i] = MFMA(af[mi][1], bfr[i][1], acc[mi][q*4+i]);
        }
      __builtin_amdgcn_s_setprio(0);
      if(q == 1) asm volatile("s_waitcnt vmcnt(4)" ::: "memory");
      if(q == 3) asm volatile("s_waitcnt vmcnt(2)" ::: "memory");
      __builtin_amdgcn_s_barrier();          // close
      __builtin_amdgcn_sched_barrier(0);
    }
  }

  #pragma unroll
  for(int mi=0;mi<2;mi++){
    int row = m0 + wid*32 + mi*16 + g*4;
    #pragma unroll
    for(int i=0;i<16;i++){
      int col = n0 + i*16 + lr;
      #pragma unroll
      for(int r=0;r<4;r++)
        out[(size_t)(row + r)*N + col] = acc[mi][i][r];
    }
  }
}

// ---------------- head GEMM fallback (small-ws only): BK=32 reg-staged B
__global__ __launch_bounds__(256) void k_gemm_f32b(const u16* __restrict__ A,
                                                   const float* __restrict__ B,
                                                   float* __restrict__ out,
                                                   int M, int N, int K, int m_base){
  __shared__ __align__(16) u16 As[128*32];
  __shared__ __align__(16) u16 Bs[128*32];
  int t = threadIdx.x, l = t & 63, w = t >> 6;
  int g = l >> 4, lr = l & 15;
  int wr = w >> 1, wc = w & 1;
  int m0 = m_base + blockIdx.y*128, n0 = blockIdx.x*128;
  f32x4 acc[4][4];
  #pragma unroll
  for(int i=0;i<4;i++)
    #pragma unroll
    for(int j=0;j<4;j++) acc[i][j] = f32x4{0.f,0.f,0.f,0.f};

  int r0 = t >> 2, c0 = (t & 3)*8;
  const u16* pa0 = A + (size_t)(m0 + r0)*K + c0;
  const u16* pa1 = A + (size_t)(m0 + r0 + 64)*K + c0;
  u16* la0 = As + t*8;  u16* la1 = As + (t+256)*8;
  int br = t >> 1, bc = (t & 1)*16;
  const float* pb = B + (size_t)(n0 + br)*K + bc;

  for(int k0=0; k0<K; k0+=32){
    gl_lds16(pa0, la0); gl_lds16(pa1, la1);
    pa0 += 32; pa1 += 32;
    float4 f0 = ((const float4*)pb)[0];
    float4 f1 = ((const float4*)pb)[1];
    float4 f2 = ((const float4*)pb)[2];
    float4 f3 = ((const float4*)pb)[3];
    pb += 32;
    ushort4 u0{f2bf(f0.x),f2bf(f0.y),f2bf(f0.z),f2bf(f0.w)};
    ushort4 u1{f2bf(f1.x),f2bf(f1.y),f2bf(f1.z),f2bf(f1.w)};
    ushort4 u2{f2bf(f2.x),f2bf(f2.y),f2bf(f2.z),f2bf(f2.w)};
    ushort4 u3{f2bf(f3.x),f2bf(f3.y),f2bf(f3.z),f2bf(f3.w)};
    *(ushort4*)&Bs[br*32 + bc +  0] = u0;
    *(ushort4*)&Bs[br*32 + bc +  4] = u1;
    *(ushort4*)&Bs[br*32 + bc +  8] = u2;
    *(ushort4*)&Bs[br*32 + bc + 12] = u3;
    __syncthreads();
    bf16x8 af[4], bfr[4];
    #pragma unroll
    for(int mi=0;mi<4;mi++) af[mi]  = ld8(&As[(wr*64 + mi*16 + lr)*32 + g*8]);
    #pragma unroll
    for(int ni=0;ni<4;ni++) bfr[ni] = ld8(&Bs[(wc*64 + ni*16 + lr)*32 + g*8]);
    #pragma unroll
    for(int mi=0;mi<4;mi++)
      #pragma unroll
      for(int ni=0;ni<4;ni++)
        acc[mi][ni] = MFMA(af[mi], bfr[ni], acc[mi][ni]);
    __syncthreads();
  }

  #pragma unroll
  for(int mi=0;mi<4;mi++){
    int row = m0 + wr*64 + mi*16 + g*4;
    #pragma unroll
    for(int ni=0;ni<4;ni++){
      int col = n0 + wc*64 + ni*16 + lr;
      #pragma unroll
      for(int r=0;r<4;r++)
        out[(size_t)(row + r)*N + col] = acc[mi][ni][r];
    }
  }
}

// ---------------- flash attention, causal + ALiBi, GQA (H=16, KVH=4, HD=64)
__global__ __launch_bounds__(256) void k_attn(const u16* __restrict__ qkv,
                                              u16* __restrict__ atto){
  __shared__ __align__(16) u16 Ksm[64*72];
  __shared__ __align__(16) u16 Vsm[64*72];
  __shared__ __align__(16) u16 Psm[4][16*72];
  int t = threadIdx.x, l = t & 63, w = t >> 6, g = l >> 4, lr = l & 15;
  int bh = blockIdx.y; int b = bh >> 4, h = bh & 15, kvh = h >> 2;
  int qb = blockIdx.x * 64;
  const float L2E = 1.44269504088896f;
  const float C1  = 0.125f * L2E;
  float slopeL = exp2f(-0.5f*(float)(h+1)) * L2E;
  float sLkt[4];
  #pragma unroll
  for(int kt=0;kt<4;kt++) sLkt[kt] = slopeL*(float)(kt*16+lr);

  int qrow = qb + w*16 + lr;
  const u16* qp = qkv + (size_t)(b*2048 + qrow)*1536 + h*64;
  bf16x8 qf0 = ld8(qp + g*8);
  bf16x8 qf1 = ld8(qp + 32 + g*8);

  bf16_t onev = (bf16_t)1.0f;
  bf16x8 onesb = {onev,onev,onev,onev,onev,onev,onev,onev};

  f32x4 oacc[4];
  #pragma unroll
  for(int i=0;i<4;i++) oacc[i] = f32x4{0.f,0.f,0.f,0.f};
  f32x4 lsum = f32x4{0.f,0.f,0.f,0.f};

  int nkb = blockIdx.x + 1;
  for(int kb=0; kb<nkb; kb++){
    __syncthreads();
    #pragma unroll
    for(int i=0;i<2;i++){
      int tt = t + i*256;
      int key = tt >> 3, ho = (tt & 7)*8;
      const u16* src = qkv + (size_t)(b*2048 + kb*64 + key)*1536 + 1024 + kvh*64 + ho;
      *(int4*)&Ksm[key*72 + ho] = *(const int4*)src;
    }
    {
      int key0 = (t>>3)*2, hd0 = (t&7)*8;
      const u16* v0 = qkv + (size_t)(b*2048 + kb*64 + key0)*1536 + 1280 + kvh*64 + hd0;
      int4 A0 = *(const int4*)v0;
      int4 A1 = *(const int4*)(v0 + 1536);
      const u16* ua = (const u16*)&A0; const u16* ub = (const u16*)&A1;
      #pragma unroll
      for(int j=0;j<8;j++){
        int row = hd0 + j;
        int colp = key0 ^ ((row>>3)*8);
        unsigned pr = (unsigned)ua[j] | ((unsigned)ub[j]<<16);
        *(unsigned*)&Vsm[row*72 + colp] = pr;
      }
    }
    __syncthreads();
    f32x4 sacc[4];
    #pragma unroll
    for(int kt=0;kt<4;kt++) sacc[kt] = f32x4{0.f,0.f,0.f,0.f};
    #pragma unroll
    for(int kt=0;kt<4;kt++){
      bf16x8 kf0 = ld8(&Ksm[(kt*16+lr)*72 + g*8]);
      bf16x8 kf1 = ld8(&Ksm[(kt*16+lr)*72 + 32 + g*8]);
      sacc[kt] = MFMA(qf0, kf0, sacc[kt]);
      sacc[kt] = MFMA(qf1, kf1, sacc[kt]);
    }
    #pragma unroll
    for(int r=0;r<4;r++){
      int q = qb + w*16 + g*4 + r;
      float base = slopeL*(float)(kb*64 - q) - 8.0f*L2E;
      #pragma unroll
      for(int kt=0;kt<4;kt++){
        int key = kb*64 + kt*16 + lr;
        float f = fmaf(sacc[kt][r], C1, base + sLkt[kt]);
        float p = (key <= q) ? exp2f(f) : 0.f;
        Psm[w][(g*4+r)*72 + kt*16 + lr] = f2bf(p);
      }
    }
    #pragma unroll
    for(int ks=0;ks<2;ks++){
      bf16x8 pf = ld8(&Psm[w][lr*72 + ks*32 + g*8]);
      lsum = MFMA(pf, onesb, lsum);
      #pragma unroll
      for(int ht=0;ht<4;ht++){
        int row = ht*16 + lr;
        int colp = (ks*32 + g*8) ^ ((row>>3)*8);
        bf16x8 vf = ld8(&Vsm[row*72 + colp]);
        oacc[ht] = MFMA(pf, vf, oacc[ht]);
      }
    }
  }
  #pragma unroll
  for(int ht=0;ht<4;ht++){
    #pragma unroll
    for(int r=0;r<4;r++){
      float o = oacc[ht][r] / lsum[r];
      atto[(size_t)(b*2048 + qb + w*16 + g*4 + r)*1024 + h*64 + ht*16 + lr] = f2bf(o);
    }
  }
}

extern "C" void kernel_launch(void* const* d_in, const int* in_sizes, int n_in,
                              void* d_out, int out_size, void* d_ws, size_t ws_size,
                              hipStream_t stream) {
  const float* tok_emb = (const float*)d_in[0];
  const float* ln1_s   = (const float*)d_in[1];
  const float* ln1_b   = (const float*)d_in[2];
  const float* qkv_w   = (const float*)d_in[3];
  const float* qkv_b   = (const float*)d_in[4];
  const float* proj_w  = (const float*)d_in[5];
  const float* proj_b  = (const float*)d_in[6];
  const float* ln2_s   = (const float*)d_in[7];
  const float* ln2_b   = (const float*)d_in[8];
  const float* fc1_w   = (const float*)d_in[9];
  const float* fc1_b   = (const float*)d_in[10];
  const float* fc2_w   = (const float*)d_in[11];
  const float* fc2_b   = (const float*)d_in[12];
  const float* lnf_s   = (const float*)d_in[13];
  const float* lnf_b   = (const float*)d_in[14];
  const int*   idx     = (const int*)d_in[15];

  // scratch plan inside d_out (524 MB, f32 logits written last):
  char* ob = (char*)d_out;
  float* xf32  = (float*)(ob);                                 //  0   .. 16.8 MB
  u16* qkv_bf  = (u16*)(ob + (size_t)16777216);                // 16.8 .. 29.4
  u16* atto_bf = (u16*)(ob + (size_t)29360128);                // 29.4 .. 37.7
  u16* mid_bf  = (u16*)(ob + (size_t)37748736);                // 37.7 .. 71.3
  u16* wt_qkv  = (u16*)(ob + (size_t)71303168);                // 71.3 .. 83.9
  u16* wt_proj = (u16*)(ob + (size_t)83886080);                // 83.9 .. 92.3
  u16* wt_fc1  = (u16*)(ob + (size_t)92274688);                // 92.3 ..125.8
  u16* wt_fc2  = (u16*)(ob + (size_t)125829120);               //125.8 ..159.4
  u16* h_bf    = (u16*)d_ws;                                   //  8.4 MB
  float* out   = (float*)d_out;

  bool big_ws = ws_size >= (size_t)(8388608 + 65536000);
  // fallback te: rows 2304..2816 of output (f32 bytes 294912000..360448000)
  u16* te_bf = big_ws ? (u16*)((char*)d_ws + 8388608)
                      : (u16*)(ob + (size_t)294912000);

  k_conv<<<32000, 256, 0, stream>>>(tok_emb, te_bf, 8192000);
  k_embed<<<4096, 256, 0, stream>>>(idx, tok_emb, xf32);
  k_convT<<<dim3(48,32,4), 256, 0, stream>>>(qkv_w,  wt_qkv, 1024, 1536);
  k_convT<<<dim3(32,32,4), 256, 0, stream>>>(proj_w, wt_proj, 1024, 1024);
  k_convT<<<dim3(128,32,4), 256, 0, stream>>>(fc1_w, wt_fc1, 1024, 4096);
  k_convT<<<dim3(32,128,4), 256, 0, stream>>>(fc2_w, wt_fc2, 4096, 1024);

  for(int l=0; l<4; l++){
    k_ln<<<4096, 256, 0, stream>>>(xf32, ln1_s + (size_t)l*1024, ln1_b + (size_t)l*1024, h_bf);
    k_gemm<0,0><<<dim3(12,32), 256, 0, stream>>>(h_bf, wt_qkv + (size_t)l*1536*1024,
                                                 qkv_b + (size_t)l*1536,
                                                 qkv_bf, nullptr, 4096, 1536, 1024, 0);
    k_attn<<<dim3(32,32), 256, 0, stream>>>(qkv_bf, atto_bf);
    k_gemm_n64<<<dim3(16,32), 256, 0, stream>>>(atto_bf, wt_proj + (size_t)l*1024*1024,
                                                proj_b + (size_t)l*1024,
                                                xf32, 4096, 1024, 1024);
    k_ln<<<4096, 256, 0, stream>>>(xf32, ln2_s + (size_t)l*1024, ln2_b + (size_t)l*1024, h_bf);
    k_gemm<2,0><<<dim3(32,32), 256, 0, stream>>>(h_bf, wt_fc1 + (size_t)l*4096*1024,
                                                 fc1_b + (size_t)l*4096,
                                                 mid_bf, nullptr, 4096, 4096, 1024, 0);
    k_gemm_n64<<<dim3(16,32), 256, 0, stream>>>(mid_bf, wt_fc2 + (size_t)l*1024*4096,
                                                fc2_b + (size_t)l*1024,
                                                xf32, 4096, 1024, 4096);
  }
  k_ln<<<4096, 256, 0, stream>>>(xf32, lnf_s, lnf_b, h_bf);

  if(big_ws){
    k_gemm256<<<dim3(16,125), 512, 0, stream>>>(h_bf, te_bf, out,
                                                4096, 32000, 1024, 0);
  } else {
    k_gemm256<<<dim3(9,125), 512, 0, stream>>>(h_bf, te_bf, out,
                                               4096, 32000, 1024, 0);
    k_gemm256<<<dim3(5,125), 512, 0, stream>>>(h_bf, te_bf, out,
                                               4096, 32000, 1024, 2816);
    k_gemm_f32b<<<dim3(250,4), 256, 0, stream>>>(h_bf, tok_emb, out,
                                                 4096, 32000, 1024, 2304);
  }
}

// Round 18
// 1593.102 us; speedup vs baseline: 1.1047x; 1.0067x over previous
//
#include <hip/hip_runtime.h>

#define DEV __device__ __forceinline__
typedef unsigned short u16;
typedef __bf16 bf16_t;
typedef bf16_t bf16x8 __attribute__((ext_vector_type(8)));
typedef float f32x4 __attribute__((ext_vector_type(4)));

DEV u16 f2bf(float f){ unsigned u=__float_as_uint(f); return (u16)((u + 0x7fffu + ((u>>16)&1u))>>16); }

DEV void gl_lds16(const void* g, void* l){
  __builtin_amdgcn_global_load_lds((__attribute__((address_space(1))) void*)g,
                                   (__attribute__((address_space(3))) void*)l, 16, 0, 0);
}
DEV f32x4 MFMA(bf16x8 a, bf16x8 b, f32x4 c){
  return __builtin_amdgcn_mfma_f32_16x16x32_bf16(a, b, c, 0, 0, 0);
}
DEV bf16x8 ld8(const u16* p){ return *(const bf16x8*)p; }

// ---------------- embedding lookup: x[row][:] = emb[idx[row]][:]
__global__ __launch_bounds__(256) void k_embed(const int* __restrict__ idx,
                                               const float* __restrict__ emb,
                                               float* __restrict__ x){
  int row = blockIdx.x;
  int tok = idx[row];
  const float4* s = (const float4*)(emb + (size_t)tok*1024);
  float4* d = (float4*)(x + (size_t)row*1024);
  d[threadIdx.x] = s[threadIdx.x];
}

// ---------------- layernorm (fp32 in) -> bf16 out, row = 1024
__global__ __launch_bounds__(256) void k_ln(const float* __restrict__ x,
                                            const float* __restrict__ sc,
                                            const float* __restrict__ bi,
                                            u16* __restrict__ out){
  int row = blockIdx.x;
  const float* xr = x + (size_t)row*1024;
  float4 v = ((const float4*)xr)[threadIdx.x];
  float s = v.x+v.y+v.z+v.w;
  float q = v.x*v.x+v.y*v.y+v.z*v.z+v.w*v.w;
  #pragma unroll
  for(int m=1;m<64;m<<=1){ s += __shfl_xor(s,m); q += __shfl_xor(q,m); }
  __shared__ float ss[4], sq[4];
  int w = threadIdx.x>>6;
  if((threadIdx.x&63)==0){ ss[w]=s; sq[w]=q; }
  __syncthreads();
  s = ss[0]+ss[1]+ss[2]+ss[3];
  q = sq[0]+sq[1]+sq[2]+sq[3];
  float mu = s*(1.f/1024.f);
  float var = q*(1.f/1024.f) - mu*mu;
  float rs = rsqrtf(var + 1e-5f);
  float4 sv = ((const float4*)sc)[threadIdx.x];
  float4 bv = ((const float4*)bi)[threadIdx.x];
  ushort4 o;
  o.x = f2bf((v.x-mu)*rs*sv.x + bv.x);
  o.y = f2bf((v.y-mu)*rs*sv.y + bv.y);
  o.z = f2bf((v.z-mu)*rs*sv.z + bv.z);
  o.w = f2bf((v.w-mu)*rs*sv.w + bv.w);
  *(ushort4*)(out + (size_t)row*1024 + threadIdx.x*4) = o;
}

// ---------------- transpose + convert (64x64, vectorized): W[K][N] f32 -> Wt[N][K] bf16
__global__ __launch_bounds__(256) void k_convT(const float* __restrict__ W,
                                               u16* __restrict__ Wt, int K, int N){
  __shared__ float tile[64][68];
  size_t loff = (size_t)blockIdx.z * K * N;
  W  += loff;  Wt += loff;
  int n0 = blockIdx.x*64, k0 = blockIdx.y*64;
  int tx = threadIdx.x & 15, ty = threadIdx.x >> 4;   // 16 x 16
  #pragma unroll
  for(int r=0;r<4;r++){
    int row = ty + r*16;
    float4 v = *(const float4*)&W[(size_t)(k0+row)*N + n0 + tx*4];
    *(float4*)&tile[row][tx*4] = v;
  }
  __syncthreads();
  int nn = threadIdx.x >> 2, kq = threadIdx.x & 3;
  #pragma unroll
  for(int r=0;r<4;r++){
    int k = (kq + r*4)*4;
    ushort4 o;
    o.x = f2bf(tile[k+0][nn]); o.y = f2bf(tile[k+1][nn]);
    o.z = f2bf(tile[k+2][nn]); o.w = f2bf(tile[k+3][nn]);
    *(ushort4*)&Wt[(size_t)(n0+nn)*K + k0 + k] = o;
  }
}

// ---------------- plain convert f32 -> bf16 (tok_emb), 4 elems/thread
__global__ __launch_bounds__(256) void k_conv(const float* __restrict__ in,
                                              u16* __restrict__ out, int n4){
  int i = blockIdx.x*256 + threadIdx.x;
  if(i < n4){
    float4 v = ((const float4*)in)[i];
    ushort4 o; o.x=f2bf(v.x); o.y=f2bf(v.y); o.z=f2bf(v.z); o.w=f2bf(v.w);
    ((ushort4*)out)[i] = o;
  }
}

// ---------------- GEMM 128x128 (2-barrier): C = A * Bt^T, BK=64, XOR swizzle
template<int EPI, int SWAP>
__global__ __launch_bounds__(256) void k_gemm(const u16* __restrict__ A,
                                              const u16* __restrict__ Bt,
                                              const float* __restrict__ bias,
                                              void* __restrict__ out,
                                              float* __restrict__ res,
                                              int M, int N, int K, int m_base){
  __shared__ __align__(16) u16 As[128*64];
  __shared__ __align__(16) u16 Bs[128*64];
  int t = threadIdx.x, l = t & 63, w = t >> 6;
  int g = l >> 4, lr = l & 15;
  int wr = w >> 1, wc = w & 1;
  int m0, n0;
  if constexpr(SWAP){ m0 = m_base + blockIdx.x*128; n0 = blockIdx.y*128; }
  else              { m0 = m_base + blockIdx.y*128; n0 = blockIdx.x*128; }
  f32x4 acc[4][4];
  #pragma unroll
  for(int i=0;i<4;i++)
    #pragma unroll
    for(int j=0;j<4;j++) acc[i][j] = f32x4{0.f,0.f,0.f,0.f};

  int sr = t >> 3;
  int sc = (((t & 7) ^ (sr & 7)) * 8);
  const u16* pa = A  + (size_t)(m0 + sr)*K + sc;
  const u16* pb = Bt + (size_t)(n0 + sr)*K + sc;
  u16* lda = As + t*8;
  u16* ldb = Bs + t*8;
  const int rs_a = (lr & 7)*8;

  for(int k0=0; k0<K; k0+=64){
    #pragma unroll
    for(int i=0;i<4;i++){
      gl_lds16(pa + (size_t)(i*32)*K, lda + i*2048);
      gl_lds16(pb + (size_t)(i*32)*K, ldb + i*2048);
    }
    pa += 64; pb += 64;
    __syncthreads();
    bf16x8 af[4][2], bfr[4][2];
    #pragma unroll
    for(int mi=0;mi<4;mi++){
      int row = wr*64 + mi*16 + lr;
      af[mi][0] = ld8(&As[row*64 + ((g*8     ) ^ rs_a)]);
      af[mi][1] = ld8(&As[row*64 + ((g*8 + 32) ^ rs_a)]);
    }
    #pragma unroll
    for(int ni=0;ni<4;ni++){
      int row = wc*64 + ni*16 + lr;
      bfr[ni][0] = ld8(&Bs[row*64 + ((g*8     ) ^ rs_a)]);
      bfr[ni][1] = ld8(&Bs[row*64 + ((g*8 + 32) ^ rs_a)]);
    }
    #pragma unroll
    for(int mi=0;mi<4;mi++)
      #pragma unroll
      for(int ni=0;ni<4;ni++){
        acc[mi][ni] = MFMA(af[mi][0], bfr[ni][0], acc[mi][ni]);
        acc[mi][ni] = MFMA(af[mi][1], bfr[ni][1], acc[mi][ni]);
      }
    __syncthreads();
  }

  float bv[4];
  #pragma unroll
  for(int ni=0;ni<4;ni++){
    if constexpr(EPI==3) bv[ni] = 0.f;
    else bv[ni] = bias[n0 + wc*64 + ni*16 + lr];
  }
  #pragma unroll
  for(int mi=0;mi<4;mi++){
    int row = m0 + wr*64 + mi*16 + g*4;
    #pragma unroll
    for(int ni=0;ni<4;ni++){
      int col = n0 + wc*64 + ni*16 + lr;
      #pragma unroll
      for(int r=0;r<4;r++){
        float v = acc[mi][ni][r] + bv[ni];
        size_t oidx = (size_t)(row + r)*N + col;
        if constexpr(EPI==0){
          ((u16*)out)[oidx] = f2bf(v);
        } else if constexpr(EPI==1){
          res[oidx] += v;
        } else if constexpr(EPI==2){
          float gv = 0.5f*v*(1.f + erff(v*0.70710678118654752f));
          ((u16*)out)[oidx] = f2bf(gv);
        } else {
          ((float*)out)[oidx] = v;   // f32 logits
        }
      }
    }
  }
}

// ---------------- GEMM 128x64 narrow (proj/fc2): 512 blocks -> 2/CU occupancy
__global__ __launch_bounds__(256) void k_gemm_n64(const u16* __restrict__ A,
                                                  const u16* __restrict__ Bt,
                                                  const float* __restrict__ bias,
                                                  float* __restrict__ res,
                                                  int M, int N, int K){
  __shared__ __align__(16) u16 As[128*64];
  __shared__ __align__(16) u16 Bs[64*64];
  int t = threadIdx.x, l = t & 63, w = t >> 6;
  int g = l >> 4, lr = l & 15;
  int wr = w >> 1, wc = w & 1;
  int m0 = blockIdx.y*128, n0 = blockIdx.x*64;
  f32x4 acc[4][2];
  #pragma unroll
  for(int i=0;i<4;i++)
    #pragma unroll
    for(int j=0;j<2;j++) acc[i][j] = f32x4{0.f,0.f,0.f,0.f};

  int sr = t >> 3;
  int sc = (((t & 7) ^ (sr & 7)) * 8);
  const u16* pa = A  + (size_t)(m0 + sr)*K + sc;
  const u16* pb = Bt + (size_t)(n0 + sr)*K + sc;
  u16* lda = As + t*8;
  u16* ldb = Bs + t*8;
  const int rs_a = (lr & 7)*8;

  for(int k0=0; k0<K; k0+=64){
    #pragma unroll
    for(int i=0;i<4;i++)
      gl_lds16(pa + (size_t)(i*32)*K, lda + i*2048);
    #pragma unroll
    for(int i=0;i<2;i++)
      gl_lds16(pb + (size_t)(i*32)*K, ldb + i*2048);
    pa += 64; pb += 64;
    __syncthreads();
    bf16x8 af[4][2], bfr[2][2];
    #pragma unroll
    for(int mi=0;mi<4;mi++){
      int row = wr*64 + mi*16 + lr;
      af[mi][0] = ld8(&As[row*64 + ((g*8     ) ^ rs_a)]);
      af[mi][1] = ld8(&As[row*64 + ((g*8 + 32) ^ rs_a)]);
    }
    #pragma unroll
    for(int ni=0;ni<2;ni++){
      int row = wc*32 + ni*16 + lr;
      bfr[ni][0] = ld8(&Bs[row*64 + ((g*8     ) ^ rs_a)]);
      bfr[ni][1] = ld8(&Bs[row*64 + ((g*8 + 32) ^ rs_a)]);
    }
    #pragma unroll
    for(int mi=0;mi<4;mi++)
      #pragma unroll
      for(int ni=0;ni<2;ni++){
        acc[mi][ni] = MFMA(af[mi][0], bfr[ni][0], acc[mi][ni]);
        acc[mi][ni] = MFMA(af[mi][1], bfr[ni][1], acc[mi][ni]);
      }
    __syncthreads();
  }

  float bv[2];
  #pragma unroll
  for(int ni=0;ni<2;ni++) bv[ni] = bias[n0 + wc*32 + ni*16 + lr];
  #pragma unroll
  for(int mi=0;mi<4;mi++){
    int row = m0 + wr*64 + mi*16 + g*4;
    #pragma unroll
    for(int ni=0;ni<2;ni++){
      int col = n0 + wc*32 + ni*16 + lr;
      #pragma unroll
      for(int r=0;r<4;r++)
        res[(size_t)(row + r)*N + col] += acc[mi][ni][r] + bv[ni];
    }
  }
}

// ---------------- GEMM 256x256 8-phase (head) — r15 schedule (proven ~350us)
__global__ __launch_bounds__(512) void k_gemm256(const u16* __restrict__ A,
                                                 const u16* __restrict__ Bt,
                                                 float* __restrict__ out,
                                                 int M, int N, int K, int m_base){
  __shared__ __align__(16) u16 As[2][256*64];
  __shared__ __align__(16) u16 Bs[2][256*64];
  int t = threadIdx.x, l = t & 63, wid = t >> 6;
  int g = l >> 4, lr = l & 15;
  int m0 = m_base + blockIdx.x*256, n0 = blockIdx.y*256;
  f32x4 acc[2][16];
  #pragma unroll
  for(int mi=0;mi<2;mi++)
    #pragma unroll
    for(int i=0;i<16;i++) acc[mi][i] = f32x4{0.f,0.f,0.f,0.f};

  int srow = t >> 3;
  int scol = ((t & 7) ^ (srow & 7)) * 8;
  const int rs = (lr & 7) * 8;
  int nt = K >> 6;

  auto stage_half = [&](int jj, int h){
    int buf = jj & 1; int k0s = jj << 6;
    if(h < 2){
      #pragma unroll
      for(int c=0;c<2;c++){
        int rr = h*128 + c*64 + srow;
        gl_lds16(A + (size_t)(m0 + rr)*K + k0s + scol,
                 &As[buf][rr*64 + (t&7)*8]);
      }
    } else {
      #pragma unroll
      for(int c=0;c<2;c++){
        int rr = (h-2)*128 + c*64 + srow;
        gl_lds16(Bt + (size_t)(n0 + rr)*K + k0s + scol,
                 &Bs[buf][rr*64 + (t&7)*8]);
      }
    }
  };

  stage_half(0,0); stage_half(0,1); stage_half(0,2); stage_half(0,3);
  asm volatile("s_waitcnt vmcnt(2)" ::: "memory");
  __builtin_amdgcn_s_barrier();
  __builtin_amdgcn_sched_barrier(0);

  bf16x8 af[2][2];
  for(int j=0; j<nt; ++j){
    const u16* Ab = As[j & 1];
    const u16* Bb = Bs[j & 1];
    bool pf = (j + 1 < nt);
    #pragma unroll
    for(int q=0; q<4; ++q){
      if(q == 0){
        #pragma unroll
        for(int mi=0;mi<2;mi++){
          int row = wid*32 + mi*16 + lr;
          af[mi][0] = ld8(&Ab[row*64 + ((g*8     ) ^ rs)]);
          af[mi][1] = ld8(&Ab[row*64 + ((g*8 + 32) ^ rs)]);
        }
      }
      bf16x8 bfr[4][2];
      #pragma unroll
      for(int i=0;i<4;i++){
        int row = (q*4 + i)*16 + lr;
        bfr[i][0] = ld8(&Bb[row*64 + ((g*8     ) ^ rs)]);
        bfr[i][1] = ld8(&Bb[row*64 + ((g*8 + 32) ^ rs)]);
      }
      if(pf) stage_half(j+1, q);
      __builtin_amdgcn_s_barrier();
      __builtin_amdgcn_sched_barrier(0);
      __builtin_amdgcn_s_setprio(1);
      #pragma unroll
      for(int mi=0;mi<2;mi++)
        #pragma unroll
        for(int i=0;i<4;i++){
          acc[mi][q*4+i] = MFMA(af[mi][0], bfr[i][0], acc[mi][q*4+i]);
          acc[mi][q*4+i] = MFMA(af[mi][1], bfr[i][1], acc[mi][q*4+i]);
        }
      __builtin_amdgcn_s_setprio(0);
      if(q == 1) asm volatile("s_waitcnt vmcnt(4)" ::: "memory");
      if(q == 3) asm volatile("s_waitcnt vmcnt(2)" ::: "memory");
      __builtin_amdgcn_s_barrier();
      __builtin_amdgcn_sched_barrier(0);
    }
  }

  #pragma unroll
  for(int mi=0;mi<2;mi++){
    int row = m0 + wid*32 + mi*16 + g*4;
    #pragma unroll
    for(int i=0;i<16;i++){
      int col = n0 + i*16 + lr;
      #pragma unroll
      for(int r=0;r<4;r++)
        out[(size_t)(row + r)*N + col] = acc[mi][i][r];
    }
  }
}

// ---------------- head GEMM fallback (small-ws only): BK=32 reg-staged B
__global__ __launch_bounds__(256) void k_gemm_f32b(const u16* __restrict__ A,
                                                   const float* __restrict__ B,
                                                   float* __restrict__ out,
                                                   int M, int N, int K, int m_base){
  __shared__ __align__(16) u16 As[128*32];
  __shared__ __align__(16) u16 Bs[128*32];
  int t = threadIdx.x, l = t & 63, w = t >> 6;
  int g = l >> 4, lr = l & 15;
  int wr = w >> 1, wc = w & 1;
  int m0 = m_base + blockIdx.y*128, n0 = blockIdx.x*128;
  f32x4 acc[4][4];
  #pragma unroll
  for(int i=0;i<4;i++)
    #pragma unroll
    for(int j=0;j<4;j++) acc[i][j] = f32x4{0.f,0.f,0.f,0.f};

  int r0 = t >> 2, c0 = (t & 3)*8;
  const u16* pa0 = A + (size_t)(m0 + r0)*K + c0;
  const u16* pa1 = A + (size_t)(m0 + r0 + 64)*K + c0;
  u16* la0 = As + t*8;  u16* la1 = As + (t+256)*8;
  int br = t >> 1, bc = (t & 1)*16;
  const float* pb = B + (size_t)(n0 + br)*K + bc;

  for(int k0=0; k0<K; k0+=32){
    gl_lds16(pa0, la0); gl_lds16(pa1, la1);
    pa0 += 32; pa1 += 32;
    float4 f0 = ((const float4*)pb)[0];
    float4 f1 = ((const float4*)pb)[1];
    float4 f2 = ((const float4*)pb)[2];
    float4 f3 = ((const float4*)pb)[3];
    pb += 32;
    ushort4 u0{f2bf(f0.x),f2bf(f0.y),f2bf(f0.z),f2bf(f0.w)};
    ushort4 u1{f2bf(f1.x),f2bf(f1.y),f2bf(f1.z),f2bf(f1.w)};
    ushort4 u2{f2bf(f2.x),f2bf(f2.y),f2bf(f2.z),f2bf(f2.w)};
    ushort4 u3{f2bf(f3.x),f2bf(f3.y),f2bf(f3.z),f2bf(f3.w)};
    *(ushort4*)&Bs[br*32 + bc +  0] = u0;
    *(ushort4*)&Bs[br*32 + bc +  4] = u1;
    *(ushort4*)&Bs[br*32 + bc +  8] = u2;
    *(ushort4*)&Bs[br*32 + bc + 12] = u3;
    __syncthreads();
    bf16x8 af[4], bfr[4];
    #pragma unroll
    for(int mi=0;mi<4;mi++) af[mi]  = ld8(&As[(wr*64 + mi*16 + lr)*32 + g*8]);
    #pragma unroll
    for(int ni=0;ni<4;ni++) bfr[ni] = ld8(&Bs[(wc*64 + ni*16 + lr)*32 + g*8]);
    #pragma unroll
    for(int mi=0;mi<4;mi++)
      #pragma unroll
      for(int ni=0;ni<4;ni++)
        acc[mi][ni] = MFMA(af[mi], bfr[ni], acc[mi][ni]);
    __syncthreads();
  }

  #pragma unroll
  for(int mi=0;mi<4;mi++){
    int row = m0 + wr*64 + mi*16 + g*4;
    #pragma unroll
    for(int ni=0;ni<4;ni++){
      int col = n0 + wc*64 + ni*16 + lr;
      #pragma unroll
      for(int r=0;r<4;r++)
        out[(size_t)(row + r)*N + col] = acc[mi][ni][r];
    }
  }
}

// ---------------- flash attention, QBLK=128 (8 waves), causal+ALiBi, GQA
// K/V tile staged once per 128 q-rows (2x amortization vs QBLK=64);
// per-wave causal tail skip keeps wasted MFMA at zero.
__global__ __launch_bounds__(512) void k_attn(const u16* __restrict__ qkv,
                                              u16* __restrict__ atto){
  __shared__ __align__(16) u16 Ksm[64*72];
  __shared__ __align__(16) u16 Vsm[64*72];
  __shared__ __align__(16) u16 Psm[8][16*72];
  int t = threadIdx.x, l = t & 63, w = t >> 6, g = l >> 4, lr = l & 15;
  int bh = blockIdx.y; int b = bh >> 4, h = bh & 15, kvh = h >> 2;
  int qb = blockIdx.x * 128;
  const float L2E = 1.44269504088896f;
  const float C1  = 0.125f * L2E;
  float slopeL = exp2f(-0.5f*(float)(h+1)) * L2E;
  float sLkt[4];
  #pragma unroll
  for(int kt=0;kt<4;kt++) sLkt[kt] = slopeL*(float)(kt*16+lr);

  int qrow = qb + w*16 + lr;
  const u16* qp = qkv + (size_t)(b*2048 + qrow)*1536 + h*64;
  bf16x8 qf0 = ld8(qp + g*8);
  bf16x8 qf1 = ld8(qp + 32 + g*8);

  bf16_t onev = (bf16_t)1.0f;
  bf16x8 onesb = {onev,onev,onev,onev,onev,onev,onev,onev};

  f32x4 oacc[4];
  #pragma unroll
  for(int i=0;i<4;i++) oacc[i] = f32x4{0.f,0.f,0.f,0.f};
  f32x4 lsum = f32x4{0.f,0.f,0.f,0.f};

  int qmax_w = qb + w*16 + 15;
  int nkb = blockIdx.x*2 + 2;   // covers keys 0 .. qb+127
  for(int kb=0; kb<nkb; kb++){
    __syncthreads();
    // K stage: 512 threads, 1 int4 each (64 rows x 64 cols)
    {
      int key = t >> 3, ho = (t & 7)*8;
      const u16* src = qkv + (size_t)(b*2048 + kb*64 + key)*1536 + 1024 + kvh*64 + ho;
      *(int4*)&Ksm[key*72 + ho] = *(const int4*)src;
    }
    // V stage transposed+swizzled: threads 0..255 (2 keys x 8 hd each)
    if(t < 256){
      int key0 = (t>>3)*2, hd0 = (t&7)*8;
      const u16* v0 = qkv + (size_t)(b*2048 + kb*64 + key0)*1536 + 1280 + kvh*64 + hd0;
      int4 A0 = *(const int4*)v0;
      int4 A1 = *(const int4*)(v0 + 1536);
      const u16* ua = (const u16*)&A0; const u16* ub = (const u16*)&A1;
      #pragma unroll
      for(int j=0;j<8;j++){
        int row = hd0 + j;
        int colp = key0 ^ ((row>>3)*8);
        unsigned pr = (unsigned)ua[j] | ((unsigned)ub[j]<<16);
        *(unsigned*)&Vsm[row*72 + colp] = pr;
      }
    }
    __syncthreads();
    if(kb*64 > qmax_w) continue;   // wave-uniform causal skip (barriers passed)
    // S = Q K^T
    f32x4 sacc[4];
    #pragma unroll
    for(int kt=0;kt<4;kt++) sacc[kt] = f32x4{0.f,0.f,0.f,0.f};
    #pragma unroll
    for(int kt=0;kt<4;kt++){
      bf16x8 kf0 = ld8(&Ksm[(kt*16+lr)*72 + g*8]);
      bf16x8 kf1 = ld8(&Ksm[(kt*16+lr)*72 + 32 + g*8]);
      sacc[kt] = MFMA(qf0, kf0, sacc[kt]);
      sacc[kt] = MFMA(qf1, kf1, sacc[kt]);
    }
    // fixed-max softmax: p = 2^(s*C1 + slopeL*(key-q) - 8*L2E)
    #pragma unroll
    for(int r=0;r<4;r++){
      int q = qb + w*16 + g*4 + r;
      float base = slopeL*(float)(kb*64 - q) - 8.0f*L2E;
      #pragma unroll
      for(int kt=0;kt<4;kt++){
        int key = kb*64 + kt*16 + lr;
        float f = fmaf(sacc[kt][r], C1, base + sLkt[kt]);
        float p = (key <= q) ? exp2f(f) : 0.f;
        Psm[w][(g*4+r)*72 + kt*16 + lr] = f2bf(p);
      }
    }
    // O += P V ; lsum += P * ones
    #pragma unroll
    for(int ks=0;ks<2;ks++){
      bf16x8 pf = ld8(&Psm[w][lr*72 + ks*32 + g*8]);
      lsum = MFMA(pf, onesb, lsum);
      #pragma unroll
      for(int ht=0;ht<4;ht++){
        int row = ht*16 + lr;
        int colp = (ks*32 + g*8) ^ ((row>>3)*8);
        bf16x8 vf = ld8(&Vsm[row*72 + colp]);
        oacc[ht] = MFMA(pf, vf, oacc[ht]);
      }
    }
  }
  #pragma unroll
  for(int ht=0;ht<4;ht++){
    #pragma unroll
    for(int r=0;r<4;r++){
      float o = oacc[ht][r] / lsum[r];
      atto[(size_t)(b*2048 + qb + w*16 + g*4 + r)*1024 + h*64 + ht*16 + lr] = f2bf(o);
    }
  }
}

extern "C" void kernel_launch(void* const* d_in, const int* in_sizes, int n_in,
                              void* d_out, int out_size, void* d_ws, size_t ws_size,
                              hipStream_t stream) {
  const float* tok_emb = (const float*)d_in[0];
  const float* ln1_s   = (const float*)d_in[1];
  const float* ln1_b   = (const float*)d_in[2];
  const float* qkv_w   = (const float*)d_in[3];
  const float* qkv_b   = (const float*)d_in[4];
  const float* proj_w  = (const float*)d_in[5];
  const float* proj_b  = (const float*)d_in[6];
  const float* ln2_s   = (const float*)d_in[7];
  const float* ln2_b   = (const float*)d_in[8];
  const float* fc1_w   = (const float*)d_in[9];
  const float* fc1_b   = (const float*)d_in[10];
  const float* fc2_w   = (const float*)d_in[11];
  const float* fc2_b   = (const float*)d_in[12];
  const float* lnf_s   = (const float*)d_in[13];
  const float* lnf_b   = (const float*)d_in[14];
  const int*   idx     = (const int*)d_in[15];

  // scratch plan inside d_out (524 MB, f32 logits written last):
  char* ob = (char*)d_out;
  float* xf32  = (float*)(ob);                                 //  0   .. 16.8 MB
  u16* qkv_bf  = (u16*)(ob + (size_t)16777216);                // 16.8 .. 29.4
  u16* atto_bf = (u16*)(ob + (size_t)29360128);                // 29.4 .. 37.7
  u16* mid_bf  = (u16*)(ob + (size_t)37748736);                // 37.7 .. 71.3
  u16* wt_qkv  = (u16*)(ob + (size_t)71303168);                // 71.3 .. 83.9
  u16* wt_proj = (u16*)(ob + (size_t)83886080);                // 83.9 .. 92.3
  u16* wt_fc1  = (u16*)(ob + (size_t)92274688);                // 92.3 ..125.8
  u16* wt_fc2  = (u16*)(ob + (size_t)125829120);               //125.8 ..159.4
  u16* h_bf    = (u16*)d_ws;                                   //  8.4 MB
  float* out   = (float*)d_out;

  bool big_ws = ws_size >= (size_t)(8388608 + 65536000);
  u16* te_bf = big_ws ? (u16*)((char*)d_ws + 8388608)
                      : (u16*)(ob + (size_t)294912000);

  k_conv<<<32000, 256, 0, stream>>>(tok_emb, te_bf, 8192000);
  k_embed<<<4096, 256, 0, stream>>>(idx, tok_emb, xf32);
  k_convT<<<dim3(24,16,4), 256, 0, stream>>>(qkv_w,  wt_qkv, 1024, 1536);
  k_convT<<<dim3(16,16,4), 256, 0, stream>>>(proj_w, wt_proj, 1024, 1024);
  k_convT<<<dim3(64,16,4), 256, 0, stream>>>(fc1_w, wt_fc1, 1024, 4096);
  k_convT<<<dim3(16,64,4), 256, 0, stream>>>(fc2_w, wt_fc2, 4096, 1024);

  for(int l=0; l<4; l++){
    k_ln<<<4096, 256, 0, stream>>>(xf32, ln1_s + (size_t)l*1024, ln1_b + (size_t)l*1024, h_bf);
    k_gemm<0,0><<<dim3(12,32), 256, 0, stream>>>(h_bf, wt_qkv + (size_t)l*1536*1024,
                                                 qkv_b + (size_t)l*1536,
                                                 qkv_bf, nullptr, 4096, 1536, 1024, 0);
    k_attn<<<dim3(16,32), 512, 0, stream>>>(qkv_bf, atto_bf);
    k_gemm_n64<<<dim3(16,32), 256, 0, stream>>>(atto_bf, wt_proj + (size_t)l*1024*1024,
                                                proj_b + (size_t)l*1024,
                                                xf32, 4096, 1024, 1024);
    k_ln<<<4096, 256, 0, stream>>>(xf32, ln2_s + (size_t)l*1024, ln2_b + (size_t)l*1024, h_bf);
    k_gemm<2,0><<<dim3(32,32), 256, 0, stream>>>(h_bf, wt_fc1 + (size_t)l*4096*1024,
                                                 fc1_b + (size_t)l*4096,
                                                 mid_bf, nullptr, 4096, 4096, 1024, 0);
    k_gemm_n64<<<dim3(16,32), 256, 0, stream>>>(mid_bf, wt_fc2 + (size_t)l*1024*4096,
                                                fc2_b + (size_t)l*1024,
                                                xf32, 4096, 1024, 4096);
  }
  k_ln<<<4096, 256, 0, stream>>>(xf32, lnf_s, lnf_b, h_bf);

  if(big_ws){
    k_gemm256<<<dim3(16,125), 512, 0, stream>>>(h_bf, te_bf, out,
                                                4096, 32000, 1024, 0);
  } else {
    k_gemm256<<<dim3(9,125), 512, 0, stream>>>(h_bf, te_bf, out,
                                               4096, 32000, 1024, 0);
    k_gemm256<<<dim3(5,125), 512, 0, stream>>>(h_bf, te_bf, out,
                                               4096, 32000, 1024, 2816);
    k_gemm_f32b<<<dim3(250,4), 256, 0, stream>>>(h_bf, tok_emb, out,
                                                 4096, 32000, 1024, 2304);
  }
}

// Round 19
// 1554.936 us; speedup vs baseline: 1.1318x; 1.0245x over previous
//
#include <hip/hip_runtime.h>

#define DEV __device__ __forceinline__
typedef unsigned short u16;
typedef __bf16 bf16_t;
typedef bf16_t bf16x8 __attribute__((ext_vector_type(8)));
typedef float f32x4 __attribute__((ext_vector_type(4)));

DEV u16 f2bf(float f){ unsigned u=__float_as_uint(f); return (u16)((u + 0x7fffu + ((u>>16)&1u))>>16); }

DEV void gl_lds16(const void* g, void* l){
  __builtin_amdgcn_global_load_lds((__attribute__((address_space(1))) void*)g,
                                   (__attribute__((address_space(3))) void*)l, 16, 0, 0);
}
DEV f32x4 MFMA(bf16x8 a, bf16x8 b, f32x4 c){
  return __builtin_amdgcn_mfma_f32_16x16x32_bf16(a, b, c, 0, 0, 0);
}
DEV bf16x8 ld8(const u16* p){ return *(const bf16x8*)p; }

// ---------------- fused prep: tok_emb f32->bf16 convert + embedding gather
__global__ __launch_bounds__(256) void k_prep(const float* __restrict__ emb,
                                              u16* __restrict__ te,
                                              const int* __restrict__ idx,
                                              float* __restrict__ x){
  int b = blockIdx.x;
  if(b < 32000){
    int i = b*256 + threadIdx.x;          // < 8192000
    float4 v = ((const float4*)emb)[i];
    ushort4 o; o.x=f2bf(v.x); o.y=f2bf(v.y); o.z=f2bf(v.z); o.w=f2bf(v.w);
    ((ushort4*)te)[i] = o;
  } else {
    int row = b - 32000;                  // 0..4095
    int tok = idx[row];
    ((float4*)(x + (size_t)row*1024))[threadIdx.x] =
        ((const float4*)(emb + (size_t)tok*1024))[threadIdx.x];
  }
}

// ---------------- layernorm (fp32 in) -> bf16 out, row = 1024
__global__ __launch_bounds__(256) void k_ln(const float* __restrict__ x,
                                            const float* __restrict__ sc,
                                            const float* __restrict__ bi,
                                            u16* __restrict__ out){
  int row = blockIdx.x;
  const float* xr = x + (size_t)row*1024;
  float4 v = ((const float4*)xr)[threadIdx.x];
  float s = v.x+v.y+v.z+v.w;
  float q = v.x*v.x+v.y*v.y+v.z*v.z+v.w*v.w;
  #pragma unroll
  for(int m=1;m<64;m<<=1){ s += __shfl_xor(s,m); q += __shfl_xor(q,m); }
  __shared__ float ss[4], sq[4];
  int w = threadIdx.x>>6;
  if((threadIdx.x&63)==0){ ss[w]=s; sq[w]=q; }
  __syncthreads();
  s = ss[0]+ss[1]+ss[2]+ss[3];
  q = sq[0]+sq[1]+sq[2]+sq[3];
  float mu = s*(1.f/1024.f);
  float var = q*(1.f/1024.f) - mu*mu;
  float rs = rsqrtf(var + 1e-5f);
  float4 sv = ((const float4*)sc)[threadIdx.x];
  float4 bv = ((const float4*)bi)[threadIdx.x];
  ushort4 o;
  o.x = f2bf((v.x-mu)*rs*sv.x + bv.x);
  o.y = f2bf((v.y-mu)*rs*sv.y + bv.y);
  o.z = f2bf((v.z-mu)*rs*sv.z + bv.z);
  o.w = f2bf((v.w-mu)*rs*sv.w + bv.w);
  *(ushort4*)(out + (size_t)row*1024 + threadIdx.x*4) = o;
}

// ---------------- transpose + convert (64x64, vectorized): W[K][N] f32 -> Wt[N][K] bf16
__global__ __launch_bounds__(256) void k_convT(const float* __restrict__ W,
                                               u16* __restrict__ Wt, int K, int N){
  __shared__ float tile[64][68];
  size_t loff = (size_t)blockIdx.z * K * N;
  W  += loff;  Wt += loff;
  int n0 = blockIdx.x*64, k0 = blockIdx.y*64;
  int tx = threadIdx.x & 15, ty = threadIdx.x >> 4;   // 16 x 16
  #pragma unroll
  for(int r=0;r<4;r++){
    int row = ty + r*16;
    float4 v = *(const float4*)&W[(size_t)(k0+row)*N + n0 + tx*4];
    *(float4*)&tile[row][tx*4] = v;
  }
  __syncthreads();
  int nn = threadIdx.x >> 2, kq = threadIdx.x & 3;
  #pragma unroll
  for(int r=0;r<4;r++){
    int k = (kq + r*4)*4;
    ushort4 o;
    o.x = f2bf(tile[k+0][nn]); o.y = f2bf(tile[k+1][nn]);
    o.z = f2bf(tile[k+2][nn]); o.w = f2bf(tile[k+3][nn]);
    *(ushort4*)&Wt[(size_t)(n0+nn)*K + k0 + k] = o;
  }
}

// ---------------- GEMM 128x128 (2-barrier): C = A * Bt^T, BK=64, XOR swizzle
template<int EPI, int SWAP>
__global__ __launch_bounds__(256) void k_gemm(const u16* __restrict__ A,
                                              const u16* __restrict__ Bt,
                                              const float* __restrict__ bias,
                                              void* __restrict__ out,
                                              float* __restrict__ res,
                                              int M, int N, int K, int m_base){
  __shared__ __align__(16) u16 As[128*64];
  __shared__ __align__(16) u16 Bs[128*64];
  int t = threadIdx.x, l = t & 63, w = t >> 6;
  int g = l >> 4, lr = l & 15;
  int wr = w >> 1, wc = w & 1;
  int m0, n0;
  if constexpr(SWAP){ m0 = m_base + blockIdx.x*128; n0 = blockIdx.y*128; }
  else              { m0 = m_base + blockIdx.y*128; n0 = blockIdx.x*128; }
  f32x4 acc[4][4];
  #pragma unroll
  for(int i=0;i<4;i++)
    #pragma unroll
    for(int j=0;j<4;j++) acc[i][j] = f32x4{0.f,0.f,0.f,0.f};

  int sr = t >> 3;
  int sc = (((t & 7) ^ (sr & 7)) * 8);
  const u16* pa = A  + (size_t)(m0 + sr)*K + sc;
  const u16* pb = Bt + (size_t)(n0 + sr)*K + sc;
  u16* lda = As + t*8;
  u16* ldb = Bs + t*8;
  const int rs_a = (lr & 7)*8;

  for(int k0=0; k0<K; k0+=64){
    #pragma unroll
    for(int i=0;i<4;i++){
      gl_lds16(pa + (size_t)(i*32)*K, lda + i*2048);
      gl_lds16(pb + (size_t)(i*32)*K, ldb + i*2048);
    }
    pa += 64; pb += 64;
    __syncthreads();
    bf16x8 af[4][2], bfr[4][2];
    #pragma unroll
    for(int mi=0;mi<4;mi++){
      int row = wr*64 + mi*16 + lr;
      af[mi][0] = ld8(&As[row*64 + ((g*8     ) ^ rs_a)]);
      af[mi][1] = ld8(&As[row*64 + ((g*8 + 32) ^ rs_a)]);
    }
    #pragma unroll
    for(int ni=0;ni<4;ni++){
      int row = wc*64 + ni*16 + lr;
      bfr[ni][0] = ld8(&Bs[row*64 + ((g*8     ) ^ rs_a)]);
      bfr[ni][1] = ld8(&Bs[row*64 + ((g*8 + 32) ^ rs_a)]);
    }
    #pragma unroll
    for(int mi=0;mi<4;mi++)
      #pragma unroll
      for(int ni=0;ni<4;ni++){
        acc[mi][ni] = MFMA(af[mi][0], bfr[ni][0], acc[mi][ni]);
        acc[mi][ni] = MFMA(af[mi][1], bfr[ni][1], acc[mi][ni]);
      }
    __syncthreads();
  }

  float bv[4];
  #pragma unroll
  for(int ni=0;ni<4;ni++){
    if constexpr(EPI==3) bv[ni] = 0.f;
    else bv[ni] = bias[n0 + wc*64 + ni*16 + lr];
  }
  #pragma unroll
  for(int mi=0;mi<4;mi++){
    int row = m0 + wr*64 + mi*16 + g*4;
    #pragma unroll
    for(int ni=0;ni<4;ni++){
      int col = n0 + wc*64 + ni*16 + lr;
      #pragma unroll
      for(int r=0;r<4;r++){
        float v = acc[mi][ni][r] + bv[ni];
        size_t oidx = (size_t)(row + r)*N + col;
        if constexpr(EPI==0){
          ((u16*)out)[oidx] = f2bf(v);
        } else if constexpr(EPI==1){
          res[oidx] += v;
        } else if constexpr(EPI==2){
          float gv = 0.5f*v*(1.f + erff(v*0.70710678118654752f));
          ((u16*)out)[oidx] = f2bf(gv);
        } else {
          ((float*)out)[oidx] = v;   // f32 logits
        }
      }
    }
  }
}

// ---------------- GEMM 128x64 narrow: high-occupancy even-grid variant
// EPI: 0 = +bias -> bf16 out ; 1 = +bias, res(f32) += v
template<int EPI>
__global__ __launch_bounds__(256) void k_gemm_n64(const u16* __restrict__ A,
                                                  const u16* __restrict__ Bt,
                                                  const float* __restrict__ bias,
                                                  void* __restrict__ outp,
                                                  float* __restrict__ res,
                                                  int M, int N, int K){
  __shared__ __align__(16) u16 As[128*64];
  __shared__ __align__(16) u16 Bs[64*64];
  int t = threadIdx.x, l = t & 63, w = t >> 6;
  int g = l >> 4, lr = l & 15;
  int wr = w >> 1, wc = w & 1;
  int m0 = blockIdx.y*128, n0 = blockIdx.x*64;
  f32x4 acc[4][2];
  #pragma unroll
  for(int i=0;i<4;i++)
    #pragma unroll
    for(int j=0;j<2;j++) acc[i][j] = f32x4{0.f,0.f,0.f,0.f};

  int sr = t >> 3;
  int sc = (((t & 7) ^ (sr & 7)) * 8);
  const u16* pa = A  + (size_t)(m0 + sr)*K + sc;
  const u16* pb = Bt + (size_t)(n0 + sr)*K + sc;
  u16* lda = As + t*8;
  u16* ldb = Bs + t*8;
  const int rs_a = (lr & 7)*8;

  for(int k0=0; k0<K; k0+=64){
    #pragma unroll
    for(int i=0;i<4;i++)
      gl_lds16(pa + (size_t)(i*32)*K, lda + i*2048);
    #pragma unroll
    for(int i=0;i<2;i++)
      gl_lds16(pb + (size_t)(i*32)*K, ldb + i*2048);
    pa += 64; pb += 64;
    __syncthreads();
    bf16x8 af[4][2], bfr[2][2];
    #pragma unroll
    for(int mi=0;mi<4;mi++){
      int row = wr*64 + mi*16 + lr;
      af[mi][0] = ld8(&As[row*64 + ((g*8     ) ^ rs_a)]);
      af[mi][1] = ld8(&As[row*64 + ((g*8 + 32) ^ rs_a)]);
    }
    #pragma unroll
    for(int ni=0;ni<2;ni++){
      int row = wc*32 + ni*16 + lr;
      bfr[ni][0] = ld8(&Bs[row*64 + ((g*8     ) ^ rs_a)]);
      bfr[ni][1] = ld8(&Bs[row*64 + ((g*8 + 32) ^ rs_a)]);
    }
    #pragma unroll
    for(int mi=0;mi<4;mi++)
      #pragma unroll
      for(int ni=0;ni<2;ni++){
        acc[mi][ni] = MFMA(af[mi][0], bfr[ni][0], acc[mi][ni]);
        acc[mi][ni] = MFMA(af[mi][1], bfr[ni][1], acc[mi][ni]);
      }
    __syncthreads();
  }

  float bv[2];
  #pragma unroll
  for(int ni=0;ni<2;ni++) bv[ni] = bias[n0 + wc*32 + ni*16 + lr];
  #pragma unroll
  for(int mi=0;mi<4;mi++){
    int row = m0 + wr*64 + mi*16 + g*4;
    #pragma unroll
    for(int ni=0;ni<2;ni++){
      int col = n0 + wc*32 + ni*16 + lr;
      #pragma unroll
      for(int r=0;r<4;r++){
        float v = acc[mi][ni][r] + bv[ni];
        if constexpr(EPI==0)
          ((u16*)outp)[(size_t)(row + r)*N + col] = f2bf(v);
        else
          res[(size_t)(row + r)*N + col] += v;
      }
    }
  }
}

// ---------------- GEMM 256x256 8-phase (head) — r15 schedule (proven ~350us)
__global__ __launch_bounds__(512) void k_gemm256(const u16* __restrict__ A,
                                                 const u16* __restrict__ Bt,
                                                 float* __restrict__ out,
                                                 int M, int N, int K, int m_base){
  __shared__ __align__(16) u16 As[2][256*64];
  __shared__ __align__(16) u16 Bs[2][256*64];
  int t = threadIdx.x, l = t & 63, wid = t >> 6;
  int g = l >> 4, lr = l & 15;
  int m0 = m_base + blockIdx.x*256, n0 = blockIdx.y*256;
  f32x4 acc[2][16];
  #pragma unroll
  for(int mi=0;mi<2;mi++)
    #pragma unroll
    for(int i=0;i<16;i++) acc[mi][i] = f32x4{0.f,0.f,0.f,0.f};

  int srow = t >> 3;
  int scol = ((t & 7) ^ (srow & 7)) * 8;
  const int rs = (lr & 7) * 8;
  int nt = K >> 6;

  auto stage_half = [&](int jj, int h){
    int buf = jj & 1; int k0s = jj << 6;
    if(h < 2){
      #pragma unroll
      for(int c=0;c<2;c++){
        int rr = h*128 + c*64 + srow;
        gl_lds16(A + (size_t)(m0 + rr)*K + k0s + scol,
                 &As[buf][rr*64 + (t&7)*8]);
      }
    } else {
      #pragma unroll
      for(int c=0;c<2;c++){
        int rr = (h-2)*128 + c*64 + srow;
        gl_lds16(Bt + (size_t)(n0 + rr)*K + k0s + scol,
                 &Bs[buf][rr*64 + (t&7)*8]);
      }
    }
  };

  stage_half(0,0); stage_half(0,1); stage_half(0,2); stage_half(0,3);
  asm volatile("s_waitcnt vmcnt(2)" ::: "memory");
  __builtin_amdgcn_s_barrier();
  __builtin_amdgcn_sched_barrier(0);

  bf16x8 af[2][2];
  for(int j=0; j<nt; ++j){
    const u16* Ab = As[j & 1];
    const u16* Bb = Bs[j & 1];
    bool pf = (j + 1 < nt);
    #pragma unroll
    for(int q=0; q<4; ++q){
      if(q == 0){
        #pragma unroll
        for(int mi=0;mi<2;mi++){
          int row = wid*32 + mi*16 + lr;
          af[mi][0] = ld8(&Ab[row*64 + ((g*8     ) ^ rs)]);
          af[mi][1] = ld8(&Ab[row*64 + ((g*8 + 32) ^ rs)]);
        }
      }
      bf16x8 bfr[4][2];
      #pragma unroll
      for(int i=0;i<4;i++){
        int row = (q*4 + i)*16 + lr;
        bfr[i][0] = ld8(&Bb[row*64 + ((g*8     ) ^ rs)]);
        bfr[i][1] = ld8(&Bb[row*64 + ((g*8 + 32) ^ rs)]);
      }
      if(pf) stage_half(j+1, q);
      __builtin_amdgcn_s_barrier();
      __builtin_amdgcn_sched_barrier(0);
      __builtin_amdgcn_s_setprio(1);
      #pragma unroll
      for(int mi=0;mi<2;mi++)
        #pragma unroll
        for(int i=0;i<4;i++){
          acc[mi][q*4+i] = MFMA(af[mi][0], bfr[i][0], acc[mi][q*4+i]);
          acc[mi][q*4+i] = MFMA(af[mi][1], bfr[i][1], acc[mi][q*4+i]);
        }
      __builtin_amdgcn_s_setprio(0);
      if(q == 1) asm volatile("s_waitcnt vmcnt(4)" ::: "memory");
      if(q == 3) asm volatile("s_waitcnt vmcnt(2)" ::: "memory");
      __builtin_amdgcn_s_barrier();
      __builtin_amdgcn_sched_barrier(0);
    }
  }

  #pragma unroll
  for(int mi=0;mi<2;mi++){
    int row = m0 + wid*32 + mi*16 + g*4;
    #pragma unroll
    for(int i=0;i<16;i++){
      int col = n0 + i*16 + lr;
      #pragma unroll
      for(int r=0;r<4;r++)
        out[(size_t)(row + r)*N + col] = acc[mi][i][r];
    }
  }
}

// ---------------- head GEMM fallback (small-ws only): BK=32 reg-staged B
__global__ __launch_bounds__(256) void k_gemm_f32b(const u16* __restrict__ A,
                                                   const float* __restrict__ B,
                                                   float* __restrict__ out,
                                                   int M, int N, int K, int m_base){
  __shared__ __align__(16) u16 As[128*32];
  __shared__ __align__(16) u16 Bs[128*32];
  int t = threadIdx.x, l = t & 63, w = t >> 6;
  int g = l >> 4, lr = l & 15;
  int wr = w >> 1, wc = w & 1;
  int m0 = m_base + blockIdx.y*128, n0 = blockIdx.x*128;
  f32x4 acc[4][4];
  #pragma unroll
  for(int i=0;i<4;i++)
    #pragma unroll
    for(int j=0;j<4;j++) acc[i][j] = f32x4{0.f,0.f,0.f,0.f};

  int r0 = t >> 2, c0 = (t & 3)*8;
  const u16* pa0 = A + (size_t)(m0 + r0)*K + c0;
  const u16* pa1 = A + (size_t)(m0 + r0 + 64)*K + c0;
  u16* la0 = As + t*8;  u16* la1 = As + (t+256)*8;
  int br = t >> 1, bc = (t & 1)*16;
  const float* pb = B + (size_t)(n0 + br)*K + bc;

  for(int k0=0; k0<K; k0+=32){
    gl_lds16(pa0, la0); gl_lds16(pa1, la1);
    pa0 += 32; pa1 += 32;
    float4 f0 = ((const float4*)pb)[0];
    float4 f1 = ((const float4*)pb)[1];
    float4 f2 = ((const float4*)pb)[2];
    float4 f3 = ((const float4*)pb)[3];
    pb += 32;
    ushort4 u0{f2bf(f0.x),f2bf(f0.y),f2bf(f0.z),f2bf(f0.w)};
    ushort4 u1{f2bf(f1.x),f2bf(f1.y),f2bf(f1.z),f2bf(f1.w)};
    ushort4 u2{f2bf(f2.x),f2bf(f2.y),f2bf(f2.z),f2bf(f2.w)};
    ushort4 u3{f2bf(f3.x),f2bf(f3.y),f2bf(f3.z),f2bf(f3.w)};
    *(ushort4*)&Bs[br*32 + bc +  0] = u0;
    *(ushort4*)&Bs[br*32 + bc +  4] = u1;
    *(ushort4*)&Bs[br*32 + bc +  8] = u2;
    *(ushort4*)&Bs[br*32 + bc + 12] = u3;
    __syncthreads();
    bf16x8 af[4], bfr[4];
    #pragma unroll
    for(int mi=0;mi<4;mi++) af[mi]  = ld8(&As[(wr*64 + mi*16 + lr)*32 + g*8]);
    #pragma unroll
    for(int ni=0;ni<4;ni++) bfr[ni] = ld8(&Bs[(wc*64 + ni*16 + lr)*32 + g*8]);
    #pragma unroll
    for(int mi=0;mi<4;mi++)
      #pragma unroll
      for(int ni=0;ni<4;ni++)
        acc[mi][ni] = MFMA(af[mi], bfr[ni], acc[mi][ni]);
    __syncthreads();
  }

  #pragma unroll
  for(int mi=0;mi<4;mi++){
    int row = m0 + wr*64 + mi*16 + g*4;
    #pragma unroll
    for(int ni=0;ni<4;ni++){
      int col = n0 + wc*64 + ni*16 + lr;
      #pragma unroll
      for(int r=0;r<4;r++)
        out[(size_t)(row + r)*N + col] = acc[mi][ni][r];
    }
  }
}

// ---------------- flash attention, QBLK=128 (8 waves), causal+ALiBi, GQA
// interior tiles (wave-uniform fully-unmasked) skip the per-lane causal cndmask.
__global__ __launch_bounds__(512) void k_attn(const u16* __restrict__ qkv,
                                              u16* __restrict__ atto){
  __shared__ __align__(16) u16 Ksm[64*72];
  __shared__ __align__(16) u16 Vsm[64*72];
  __shared__ __align__(16) u16 Psm[8][16*72];
  int t = threadIdx.x, l = t & 63, w = t >> 6, g = l >> 4, lr = l & 15;
  int bh = blockIdx.y; int b = bh >> 4, h = bh & 15, kvh = h >> 2;
  int qb = blockIdx.x * 128;
  const float L2E = 1.44269504088896f;
  const float C1  = 0.125f * L2E;
  float slopeL = exp2f(-0.5f*(float)(h+1)) * L2E;
  float sLkt[4];
  #pragma unroll
  for(int kt=0;kt<4;kt++) sLkt[kt] = slopeL*(float)(kt*16+lr);

  int qrow = qb + w*16 + lr;
  const u16* qp = qkv + (size_t)(b*2048 + qrow)*1536 + h*64;
  bf16x8 qf0 = ld8(qp + g*8);
  bf16x8 qf1 = ld8(qp + 32 + g*8);

  bf16_t onev = (bf16_t)1.0f;
  bf16x8 onesb = {onev,onev,onev,onev,onev,onev,onev,onev};

  f32x4 oacc[4];
  #pragma unroll
  for(int i=0;i<4;i++) oacc[i] = f32x4{0.f,0.f,0.f,0.f};
  f32x4 lsum = f32x4{0.f,0.f,0.f,0.f};

  int qmin_w = qb + w*16;
  int qmax_w = qmin_w + 15;
  int nkb = blockIdx.x*2 + 2;
  for(int kb=0; kb<nkb; kb++){
    __syncthreads();
    {
      int key = t >> 3, ho = (t & 7)*8;
      const u16* src = qkv + (size_t)(b*2048 + kb*64 + key)*1536 + 1024 + kvh*64 + ho;
      *(int4*)&Ksm[key*72 + ho] = *(const int4*)src;
    }
    if(t < 256){
      int key0 = (t>>3)*2, hd0 = (t&7)*8;
      const u16* v0 = qkv + (size_t)(b*2048 + kb*64 + key0)*1536 + 1280 + kvh*64 + hd0;
      int4 A0 = *(const int4*)v0;
      int4 A1 = *(const int4*)(v0 + 1536);
      const u16* ua = (const u16*)&A0; const u16* ub = (const u16*)&A1;
      #pragma unroll
      for(int j=0;j<8;j++){
        int row = hd0 + j;
        int colp = key0 ^ ((row>>3)*8);
        unsigned pr = (unsigned)ua[j] | ((unsigned)ub[j]<<16);
        *(unsigned*)&Vsm[row*72 + colp] = pr;
      }
    }
    __syncthreads();
    if(kb*64 > qmax_w) continue;
    f32x4 sacc[4];
    #pragma unroll
    for(int kt=0;kt<4;kt++) sacc[kt] = f32x4{0.f,0.f,0.f,0.f};
    #pragma unroll
    for(int kt=0;kt<4;kt++){
      bf16x8 kf0 = ld8(&Ksm[(kt*16+lr)*72 + g*8]);
      bf16x8 kf1 = ld8(&Ksm[(kt*16+lr)*72 + 32 + g*8]);
      sacc[kt] = MFMA(qf0, kf0, sacc[kt]);
      sacc[kt] = MFMA(qf1, kf1, sacc[kt]);
    }
    if(kb*64 + 63 <= qmin_w){
      // interior: all keys <= q for every lane -> no mask
      #pragma unroll
      for(int r=0;r<4;r++){
        int q = qb + w*16 + g*4 + r;
        float base = slopeL*(float)(kb*64 - q) - 8.0f*L2E;
        #pragma unroll
        for(int kt=0;kt<4;kt++){
          float f = fmaf(sacc[kt][r], C1, base + sLkt[kt]);
          Psm[w][(g*4+r)*72 + kt*16 + lr] = f2bf(exp2f(f));
        }
      }
    } else {
      #pragma unroll
      for(int r=0;r<4;r++){
        int q = qb + w*16 + g*4 + r;
        float base = slopeL*(float)(kb*64 - q) - 8.0f*L2E;
        #pragma unroll
        for(int kt=0;kt<4;kt++){
          int key = kb*64 + kt*16 + lr;
          float f = fmaf(sacc[kt][r], C1, base + sLkt[kt]);
          float p = (key <= q) ? exp2f(f) : 0.f;
          Psm[w][(g*4+r)*72 + kt*16 + lr] = f2bf(p);
        }
      }
    }
    #pragma unroll
    for(int ks=0;ks<2;ks++){
      bf16x8 pf = ld8(&Psm[w][lr*72 + ks*32 + g*8]);
      lsum = MFMA(pf, onesb, lsum);
      #pragma unroll
      for(int ht=0;ht<4;ht++){
        int row = ht*16 + lr;
        int colp = (ks*32 + g*8) ^ ((row>>3)*8);
        bf16x8 vf = ld8(&Vsm[row*72 + colp]);
        oacc[ht] = MFMA(pf, vf, oacc[ht]);
      }
    }
  }
  #pragma unroll
  for(int ht=0;ht<4;ht++){
    #pragma unroll
    for(int r=0;r<4;r++){
      float o = oacc[ht][r] / lsum[r];
      atto[(size_t)(b*2048 + qb + w*16 + g*4 + r)*1024 + h*64 + ht*16 + lr] = f2bf(o);
    }
  }
}

extern "C" void kernel_launch(void* const* d_in, const int* in_sizes, int n_in,
                              void* d_out, int out_size, void* d_ws, size_t ws_size,
                              hipStream_t stream) {
  const float* tok_emb = (const float*)d_in[0];
  const float* ln1_s   = (const float*)d_in[1];
  const float* ln1_b   = (const float*)d_in[2];
  const float* qkv_w   = (const float*)d_in[3];
  const float* qkv_b   = (const float*)d_in[4];
  const float* proj_w  = (const float*)d_in[5];
  const float* proj_b  = (const float*)d_in[6];
  const float* ln2_s   = (const float*)d_in[7];
  const float* ln2_b   = (const float*)d_in[8];
  const float* fc1_w   = (const float*)d_in[9];
  const float* fc1_b   = (const float*)d_in[10];
  const float* fc2_w   = (const float*)d_in[11];
  const float* fc2_b   = (const float*)d_in[12];
  const float* lnf_s   = (const float*)d_in[13];
  const float* lnf_b   = (const float*)d_in[14];
  const int*   idx     = (const int*)d_in[15];

  // scratch plan inside d_out (524 MB, f32 logits written last):
  char* ob = (char*)d_out;
  float* xf32  = (float*)(ob);                                 //  0   .. 16.8 MB
  u16* qkv_bf  = (u16*)(ob + (size_t)16777216);                // 16.8 .. 29.4
  u16* atto_bf = (u16*)(ob + (size_t)29360128);                // 29.4 .. 37.7
  u16* mid_bf  = (u16*)(ob + (size_t)37748736);                // 37.7 .. 71.3
  u16* wt_qkv  = (u16*)(ob + (size_t)71303168);                // 71.3 .. 83.9
  u16* wt_proj = (u16*)(ob + (size_t)83886080);                // 83.9 .. 92.3
  u16* wt_fc1  = (u16*)(ob + (size_t)92274688);                // 92.3 ..125.8
  u16* wt_fc2  = (u16*)(ob + (size_t)125829120);               //125.8 ..159.4
  u16* h_bf    = (u16*)d_ws;                                   //  8.4 MB
  float* out   = (float*)d_out;

  bool big_ws = ws_size >= (size_t)(8388608 + 65536000);
  u16* te_bf = big_ws ? (u16*)((char*)d_ws + 8388608)
                      : (u16*)(ob + (size_t)294912000);

  k_prep<<<36096, 256, 0, stream>>>(tok_emb, te_bf, idx, xf32);
  k_convT<<<dim3(24,16,4), 256, 0, stream>>>(qkv_w,  wt_qkv, 1024, 1536);
  k_convT<<<dim3(16,16,4), 256, 0, stream>>>(proj_w, wt_proj, 1024, 1024);
  k_convT<<<dim3(64,16,4), 256, 0, stream>>>(fc1_w, wt_fc1, 1024, 4096);
  k_convT<<<dim3(16,64,4), 256, 0, stream>>>(fc2_w, wt_fc2, 4096, 1024);

  for(int l=0; l<4; l++){
    k_ln<<<4096, 256, 0, stream>>>(xf32, ln1_s + (size_t)l*1024, ln1_b + (size_t)l*1024, h_bf);
    k_gemm_n64<0><<<dim3(24,32), 256, 0, stream>>>(h_bf, wt_qkv + (size_t)l*1536*1024,
                                                   qkv_b + (size_t)l*1536,
                                                   qkv_bf, nullptr, 4096, 1536, 1024);
    k_attn<<<dim3(16,32), 512, 0, stream>>>(qkv_bf, atto_bf);
    k_gemm_n64<1><<<dim3(16,32), 256, 0, stream>>>(atto_bf, wt_proj + (size_t)l*1024*1024,
                                                   proj_b + (size_t)l*1024,
                                                   nullptr, xf32, 4096, 1024, 1024);
    k_ln<<<4096, 256, 0, stream>>>(xf32, ln2_s + (size_t)l*1024, ln2_b + (size_t)l*1024, h_bf);
    k_gemm<2,0><<<dim3(32,32), 256, 0, stream>>>(h_bf, wt_fc1 + (size_t)l*4096*1024,
                                                 fc1_b + (size_t)l*4096,
                                                 mid_bf, nullptr, 4096, 4096, 1024, 0);
    k_gemm_n64<1><<<dim3(16,32), 256, 0, stream>>>(mid_bf, wt_fc2 + (size_t)l*1024*4096,
                                                   fc2_b + (size_t)l*1024,
                                                   nullptr, xf32, 4096, 1024, 4096);
  }
  k_ln<<<4096, 256, 0, stream>>>(xf32, lnf_s, lnf_b, h_bf);

  if(big_ws){
    k_gemm256<<<dim3(16,125), 512, 0, stream>>>(h_bf, te_bf, out,
                                                4096, 32000, 1024, 0);
  } else {
    k_gemm256<<<dim3(9,125), 512, 0, stream>>>(h_bf, te_bf, out,
                                               4096, 32000, 1024, 0);
    k_gemm256<<<dim3(5,125), 512, 0, stream>>>(h_bf, te_bf, out,
                                               4096, 32000, 1024, 2816);
    k_gemm_f32b<<<dim3(250,4), 256, 0, stream>>>(h_bf, tok_emb, out,
                                                 4096, 32000, 1024, 2304);
  }
}